// Round 6
// baseline (414.029 us; speedup 1.0000x reference)
//
#include <hip/hip_runtime.h>
#include <math.h>

#define NH 16
#define HD 64
#define HID 1024
#define SEQ 2048
#define NB 2

typedef __attribute__((ext_vector_type(8))) short short8;
typedef __attribute__((ext_vector_type(4))) float f32x4;
typedef unsigned short u16;
typedef unsigned int u32;

constexpr float LN_EPS_C = 1e-5f;
constexpr float SM_SCALE = 0.07216878364870323f; // 1/sqrt(64*3)

__device__ inline u16 f2b(float f) {
  unsigned u = __builtin_bit_cast(unsigned, f);
  u = (u + 0x7FFFu + ((u >> 16) & 1u)) >> 16;
  return (u16)u;
}
__device__ inline float b2f(u16 h) {
  unsigned u = ((unsigned)h) << 16;
  return __builtin_bit_cast(float, u);
}
__device__ inline u32 pk2(float lo, float hi) {
  return (u32)f2b(lo) | ((u32)f2b(hi) << 16);
}
__device__ inline f32x4 mfma16(short8 a, short8 b, f32x4 c) {
  return __builtin_amdgcn_mfma_f32_16x16x32_bf16(a, b, c, 0, 0, 0);
}
// swizzled read of a [rows][64] bf16 tile whose writes used slot = chunk^(row&7)
__device__ inline short8 swz8(const u16* base, int row, int hc) {
  return *reinterpret_cast<const short8*>(&base[row * 64 + 8 * (hc ^ (row & 7))]);
}

// ---------------- LayerNorm over relpos_table rows -> bf16 ----------------
__global__ __launch_bounds__(256) void ln_kernel(const float* __restrict__ tbl,
    const float* __restrict__ gamma, const float* __restrict__ beta,
    u16* __restrict__ e) {
  int row = blockIdx.x;
  int t = threadIdx.x;
  const float4* rp = reinterpret_cast<const float4*>(tbl + (size_t)row * HID);
  float4 x = rp[t];
  float s = x.x + x.y + x.z + x.w;
  float ss = x.x * x.x + x.y * x.y + x.z * x.z + x.w * x.w;
  #pragma unroll
  for (int o = 1; o < 64; o <<= 1) {
    s += __shfl_xor(s, o);
    ss += __shfl_xor(ss, o);
  }
  __shared__ float sb[4], ssb[4];
  int w = t >> 6;
  if ((t & 63) == 0) { sb[w] = s; ssb[w] = ss; }
  __syncthreads();
  s = sb[0] + sb[1] + sb[2] + sb[3];
  ss = ssb[0] + ssb[1] + ssb[2] + ssb[3];
  float mu = s * (1.0f / HID);
  float var = ss * (1.0f / HID) - mu * mu;
  float rs = rsqrtf(var + LN_EPS_C);
  float4 g = reinterpret_cast<const float4*>(gamma)[t];
  float4 bt = reinterpret_cast<const float4*>(beta)[t];
  ushort4 o4;
  o4.x = f2b((x.x - mu) * rs * g.x + bt.x);
  o4.y = f2b((x.y - mu) * rs * g.y + bt.y);
  o4.z = f2b((x.z - mu) * rs * g.z + bt.z);
  o4.w = f2b((x.w - mu) * rs * g.w + bt.w);
  *reinterpret_cast<ushort4*>(&e[(size_t)row * HID + t * 4]) = o4;
}

// ---------------- f32 -> bf16 convert ----------------
__global__ __launch_bounds__(256) void conv_bf16(const float* __restrict__ src,
    u16* __restrict__ dst, int n) {
  int i = (blockIdx.x * 256 + threadIdx.x) * 8;
  if (i >= n) return;
  float4 a = *reinterpret_cast<const float4*>(&src[i]);
  float4 c = *reinterpret_cast<const float4*>(&src[i + 4]);
  short8 o;
  o[0] = (short)f2b(a.x); o[1] = (short)f2b(a.y); o[2] = (short)f2b(a.z); o[3] = (short)f2b(a.w);
  o[4] = (short)f2b(c.x); o[5] = (short)f2b(c.y); o[6] = (short)f2b(c.z); o[7] = (short)f2b(c.w);
  *reinterpret_cast<short8*>(&dst[i]) = o;
}

// ---------------- all 6 weight transposes in one launch ----------------
struct P6 {
  const float* s[6];
  u16* d[6];
};
__global__ __launch_bounds__(256) void transp_all(P6 p) {
  __shared__ float T[32][33];
  const float* W = p.s[blockIdx.z];
  u16* Wt = p.d[blockIdx.z];
  int bn = blockIdx.x * 32, bk = blockIdx.y * 32;
  int t = threadIdx.x;
  int r = t >> 3, c4 = (t & 7) * 4;
  float4 v = *reinterpret_cast<const float4*>(&W[(size_t)(bk + r) * HID + bn + c4]);
  T[r][c4 + 0] = v.x; T[r][c4 + 1] = v.y; T[r][c4 + 2] = v.z; T[r][c4 + 3] = v.w;
  __syncthreads();
  int n = t >> 3, k4 = (t & 7) * 4;
  ushort4 o;
  o.x = f2b(T[k4 + 0][n]); o.y = f2b(T[k4 + 1][n]);
  o.z = f2b(T[k4 + 2][n]); o.w = f2b(T[k4 + 3][n]);
  *reinterpret_cast<ushort4*>(&Wt[(size_t)(bn + n) * HID + bk + k4]) = o;
}

// ---------------- bf16 MFMA GEMM: BK=64, write-XOR swizzle staging, reg prefetch ----------------
template <bool F32OUT>
__global__ __launch_bounds__(256) void gemm_bf16(const u16* __restrict__ A,
    const u16* __restrict__ Bt, const float* __restrict__ bias,
    void* __restrict__ Cout) {
  __shared__ u16 Al[8192]; // [128][64] swizzled
  __shared__ u16 Bl[8192];
  int t = threadIdx.x;
  int cb = blockIdx.x * 128, rb = blockIdx.y * 128;
  int wv = t >> 6, lane = t & 63, l15 = lane & 15, lg = lane >> 4;
  int wr = (wv >> 1) * 64, wc = (wv & 1) * 64;
  int srow = t >> 1, scb = (t & 1) * 4;
  f32x4 acc[4][4];
  #pragma unroll
  for (int i = 0; i < 4; ++i)
    #pragma unroll
    for (int j = 0; j < 4; ++j) acc[i][j] = (f32x4){0.f, 0.f, 0.f, 0.f};
  const u16* Ap = A + (size_t)(rb + srow) * HID;
  const u16* Bp = Bt + (size_t)(cb + srow) * HID;
  short8 pa[4], pb[4];
  #pragma unroll
  for (int c4 = 0; c4 < 4; ++c4) {
    pa[c4] = *reinterpret_cast<const short8*>(&Ap[(scb + c4) * 8]);
    pb[c4] = *reinterpret_cast<const short8*>(&Bp[(scb + c4) * 8]);
  }
  for (int kk = 0; kk < HID; kk += 64) {
    __syncthreads();
    #pragma unroll
    for (int c4 = 0; c4 < 4; ++c4) {
      int slot = 8 * ((scb + c4) ^ (srow & 7));
      *reinterpret_cast<short8*>(&Al[srow * 64 + slot]) = pa[c4];
      *reinterpret_cast<short8*>(&Bl[srow * 64 + slot]) = pb[c4];
    }
    __syncthreads();
    if (kk + 64 < HID) {
      #pragma unroll
      for (int c4 = 0; c4 < 4; ++c4) {
        pa[c4] = *reinterpret_cast<const short8*>(&Ap[kk + 64 + (scb + c4) * 8]);
        pb[c4] = *reinterpret_cast<const short8*>(&Bp[kk + 64 + (scb + c4) * 8]);
      }
    }
    #pragma unroll
    for (int s = 0; s < 2; ++s) {
      short8 am[4], bn[4];
      #pragma unroll
      for (int i = 0; i < 4; ++i) am[i] = swz8(Al, wr + i * 16 + l15, s * 4 + lg);
      #pragma unroll
      for (int j = 0; j < 4; ++j) bn[j] = swz8(Bl, wc + j * 16 + l15, s * 4 + lg);
      #pragma unroll
      for (int i = 0; i < 4; ++i)
        #pragma unroll
        for (int j = 0; j < 4; ++j)
          acc[i][j] = mfma16(am[i], bn[j], acc[i][j]);
    }
  }
  #pragma unroll
  for (int j = 0; j < 4; ++j) {
    float bv = bias[cb + wc + j * 16 + l15];
    #pragma unroll
    for (int i = 0; i < 4; ++i) {
      #pragma unroll
      for (int r = 0; r < 4; ++r) {
        size_t idx = (size_t)(rb + wr + i * 16 + lg * 4 + r) * HID + cb + wc + j * 16 + l15;
        float v = acc[i][j][r] + bv;
        if (F32OUT) reinterpret_cast<float*>(Cout)[idx] = v;
        else reinterpret_cast<u16*>(Cout)[idx] = f2b(v);
      }
    }
  }
}

// ---------------- rank-1 bias precompute: qrk0 = Q.rk[0], krq0 = K.rq[0] ----------------
__global__ __launch_bounds__(256) void biasqk(const u16* __restrict__ Qb,
    const u16* __restrict__ Kb, const u16* __restrict__ RKb,
    const u16* __restrict__ RQb, float* __restrict__ qrk0,
    float* __restrict__ krq0) {
  int o = blockIdx.x * 64 + (threadIdx.x >> 2);
  int sub = threadIdx.x & 3;
  int b = o >> 15, h = (o >> 11) & 15, i = o & 2047;
  size_t rbase = (size_t)(b * SEQ + i) * HID + h * HD + sub * 16;
  size_t tbase = (size_t)h * HD + sub * 16;
  float s1 = 0.f, s2 = 0.f;
  #pragma unroll
  for (int c = 0; c < 2; ++c) {
    short8 qv = *reinterpret_cast<const short8*>(&Qb[rbase + c * 8]);
    short8 rv = *reinterpret_cast<const short8*>(&RKb[tbase + c * 8]);
    short8 kv = *reinterpret_cast<const short8*>(&Kb[rbase + c * 8]);
    short8 uv = *reinterpret_cast<const short8*>(&RQb[tbase + c * 8]);
    #pragma unroll
    for (int j = 0; j < 8; ++j) {
      s1 += b2f((u16)qv[j]) * b2f((u16)rv[j]);
      s2 += b2f((u16)kv[j]) * b2f((u16)uv[j]);
    }
  }
  s1 += __shfl_xor(s1, 1); s1 += __shfl_xor(s1, 2);
  s2 += __shfl_xor(s2, 1); s2 += __shfl_xor(s2, 2);
  if (sub == 0) { qrk0[o] = s1; krq0[o] = s2; }
}

// ---------------- band bias precompute (round-5-validated G machinery) ----------------
// band[(bh + q)*512 + d] = Q[q].rk[511-d] + K[q-d].rq[511-d],  d in [0,511]
// LDS: Ks [64][64] swz @0; U @4096:
//   stage: RKB [128][64] swz @UO, RQB @UO+8192
//   G:     G1 [64 q][132 w] @UO, G2 [64 k][132 w] @UO+8448
__global__ __launch_bounds__(256, 3) void bias_kernel(
    const u16* __restrict__ Qb, const u16* __restrict__ Kb,
    const u16* __restrict__ RKb, const u16* __restrict__ RQb,
    u16* __restrict__ band) {
  __shared__ u16 smem[20992]; // 41984 B -> 3 blocks/CU
  const int KsO = 0, UO = 4096;
  const int RKO = UO, RQO = UO + 8192;
  const int G1O = UO, G2O = UO + 8448;

  int qt = blockIdx.x;
  int h = blockIdx.y, b = blockIdx.z;
  int q0 = qt * 64;
  int t = threadIdx.x;
  int wv = t >> 6, lane = t & 63, l15 = lane & 15, lg = lane >> 4;
  int qs = q0 + wv * 16;
  int hoff = h * HD;
  int bh = (b * NH + h) * SEQ;

  size_t qgrow = (size_t)(b * SEQ + qs + l15) * HID + hoff;
  short8 aq0 = *reinterpret_cast<const short8*>(&Qb[qgrow + lg * 8]);
  short8 aq1 = *reinterpret_cast<const short8*>(&Qb[qgrow + 32 + lg * 8]);

  const f32x4 Z = (f32x4){0.f, 0.f, 0.f, 0.f};
  int vr = t >> 2, vc8 = (t & 3) * 8;
  int ktlo = qt - 8; if (ktlo < 0) ktlo = 0;

  for (int kt = ktlo; kt <= qt; ++kt) {
    int k0 = kt * 64;
    int dt = qt - kt;
    int wlo = 448 - 64 * dt; if (wlo < 0) wlo = 0;
    __syncthreads(); // #1: previous iteration's gathers done
    // ---- stage K (write-XOR swizzle) ----
    {
      const u16* kg = &Kb[(size_t)(b * SEQ + k0 + vr) * HID + hoff];
      int c0 = vc8 >> 3;
      *reinterpret_cast<short8*>(&smem[KsO + vr * 64 + 8 * (c0 ^ (vr & 7))]) =
          *reinterpret_cast<const short8*>(&kg[vc8]);
      *reinterpret_cast<short8*>(&smem[KsO + vr * 64 + 8 * ((c0 + 4) ^ (vr & 7))]) =
          *reinterpret_cast<const short8*>(&kg[vc8 + 32]);
    }
    // ---- stage rk/rq bands ----
    for (int e2 = t; e2 < 1024; e2 += 256) {
      int rr = e2 >> 3, cch = e2 & 7;
      int wr2 = wlo + rr; if (wr2 > 511) wr2 = 511;
      size_t gb = (size_t)wr2 * HID + hoff + cch * 8;
      int slot = 8 * (cch ^ (rr & 7));
      *reinterpret_cast<short8*>(&smem[RKO + rr * 64 + slot]) =
          *reinterpret_cast<const short8*>(&RKb[gb]);
      *reinterpret_cast<short8*>(&smem[RQO + rr * 64 + slot]) =
          *reinterpret_cast<const short8*>(&RQb[gb]);
    }
    __syncthreads(); // #2: staging visible
    // ---- G1 = (RK_band . Q^T)^T ; G2 = (RQ_band . K^T)^T ----
    u32 g1p[16], g2p[16];
    #pragma unroll
    for (int cw = 0; cw < 8; ++cw) {
      short8 r0 = swz8(&smem[RKO], cw * 16 + l15, lg);
      short8 r1 = swz8(&smem[RKO], cw * 16 + l15, 4 + lg);
      f32x4 g = mfma16(r1, aq1, mfma16(r0, aq0, Z));
      g1p[2 * cw] = pk2(g[0], g[1]);
      g1p[2 * cw + 1] = pk2(g[2], g[3]);
    }
    short8 kw0 = swz8(&smem[KsO], wv * 16 + l15, lg);
    short8 kw1 = swz8(&smem[KsO], wv * 16 + l15, 4 + lg);
    #pragma unroll
    for (int cw = 0; cw < 8; ++cw) {
      short8 u0 = swz8(&smem[RQO], cw * 16 + l15, lg);
      short8 u1 = swz8(&smem[RQO], cw * 16 + l15, 4 + lg);
      f32x4 g = mfma16(u1, kw1, mfma16(u0, kw0, Z));
      g2p[2 * cw] = pk2(g[0], g[1]);
      g2p[2 * cw + 1] = pk2(g[2], g[3]);
    }
    __syncthreads(); // #3: band reads done; U reusable for G
    #pragma unroll
    for (int cw = 0; cw < 8; ++cw) {
      *reinterpret_cast<uint2*>(&smem[G1O + (wv * 16 + l15) * 132 + cw * 16 + lg * 4]) =
          make_uint2(g1p[2 * cw], g1p[2 * cw + 1]);
      *reinterpret_cast<uint2*>(&smem[G2O + (wv * 16 + l15) * 132 + cw * 16 + lg * 4]) =
          make_uint2(g2p[2 * cw], g2p[2 * cw + 1]);
    }
    __syncthreads(); // #4: G visible
    // ---- gather + global write ----
    #pragma unroll
    for (int c = 0; c < 4; ++c) {
      #pragma unroll
      for (int r = 0; r < 4; ++r) {
        int q = qs + lg * 4 + r;
        int k = k0 + c * 16 + l15;
        int d = q - k;
        int wi = 511 - d - wlo; if (wi < 0) wi = 0;
        float v = b2f(smem[G1O + (wv * 16 + lg * 4 + r) * 132 + wi]) +
                  b2f(smem[G2O + (c * 16 + l15) * 132 + wi]);
        if (d >= 0 && d < 512)
          band[((size_t)(bh + q) << 9) + d] = f2b(v);
      }
    }
  }
}

// ---------------- fused DeBERTa flash attention (uniform 2-barrier tiles) ----------------
// LDS: Ks [64][64] swz @0; Vt [64 d][72 k] @4096; Ps [64][72] @8704
__global__ __launch_bounds__(256, 5) void attn_mfma(
    const u16* __restrict__ Qb, const u16* __restrict__ Kb,
    const u16* __restrict__ Vb, const float* __restrict__ qrk0,
    const float* __restrict__ krq0, const u16* __restrict__ band,
    u16* __restrict__ ATT) {
  __shared__ u16 smem[13312]; // 26624 B -> 5-6 blocks/CU
  const int KsO = 0, VtO = 4096, PsO = 8704;

  int qt = (int)gridDim.x - 1 - (int)blockIdx.x; // heavy tiles first
  int h = blockIdx.y, b = blockIdx.z;
  int q0 = qt * 64;
  int t = threadIdx.x;
  int wv = t >> 6, lane = t & 63, l15 = lane & 15, lg = lane >> 4;
  int qs = q0 + wv * 16;
  int hoff = h * HD;
  int bh = (b * NH + h) * SEQ;
  const u16* bandq = band + ((size_t)bh << 9);

  size_t qgrow = (size_t)(b * SEQ + qs + l15) * HID + hoff;
  short8 aq0 = *reinterpret_cast<const short8*>(&Qb[qgrow + lg * 8]);
  short8 aq1 = *reinterpret_cast<const short8*>(&Qb[qgrow + 32 + lg * 8]);
  float qb0[4];
  #pragma unroll
  for (int r = 0; r < 4; ++r) qb0[r] = qrk0[bh + qs + lg * 4 + r];

  float m_[4], l_[4];
  f32x4 o[4];
  #pragma unroll
  for (int r = 0; r < 4; ++r) { m_[r] = -INFINITY; l_[r] = 0.f; }
  #pragma unroll
  for (int c = 0; c < 4; ++c) o[c] = (f32x4){0.f, 0.f, 0.f, 0.f};

  const f32x4 Z = (f32x4){0.f, 0.f, 0.f, 0.f};
  int vr = t >> 2, vc8 = (t & 3) * 8;

  for (int kt = 0; kt <= qt; ++kt) {
    int k0 = kt * 64;
    int dt = qt - kt;
    __syncthreads(); // #1: previous iteration fully consumed
    // ---- stage K (write-XOR swizzle) + V transposed ----
    {
      const u16* kg = &Kb[(size_t)(b * SEQ + k0 + vr) * HID + hoff];
      int c0 = vc8 >> 3;
      *reinterpret_cast<short8*>(&smem[KsO + vr * 64 + 8 * (c0 ^ (vr & 7))]) =
          *reinterpret_cast<const short8*>(&kg[vc8]);
      *reinterpret_cast<short8*>(&smem[KsO + vr * 64 + 8 * ((c0 + 4) ^ (vr & 7))]) =
          *reinterpret_cast<const short8*>(&kg[vc8 + 32]);
      const u16* vg = &Vb[(size_t)(b * SEQ + k0 + vr) * HID + hoff];
      short8 v0 = *reinterpret_cast<const short8*>(&vg[vc8]);
      short8 v1 = *reinterpret_cast<const short8*>(&vg[vc8 + 32]);
      #pragma unroll
      for (int j = 0; j < 8; ++j) smem[VtO + (vc8 + j) * 72 + vr] = (u16)v0[j];
      #pragma unroll
      for (int j = 0; j < 8; ++j) smem[VtO + (vc8 + 32 + j) * 72 + vr] = (u16)v1[j];
    }
    // ---- bias tile (overlaps the staging barrier) ----
    float kq[4];
    #pragma unroll
    for (int c = 0; c < 4; ++c) kq[c] = krq0[bh + k0 + c * 16 + l15];
    float bb[4][4];
    if (dt <= 8) {
      #pragma unroll
      for (int c = 0; c < 4; ++c) {
        #pragma unroll
        for (int r = 0; r < 4; ++r) {
          int q = qs + lg * 4 + r;
          int d = q - (k0 + c * 16 + l15);
          bb[c][r] = (d >= 0 && d < 512)
                         ? b2f(bandq[((size_t)q << 9) + d])
                         : qb0[r] + kq[c]; // d>511: rank-1; d<0: masked later
        }
      }
    } else {
      #pragma unroll
      for (int c = 0; c < 4; ++c)
        #pragma unroll
        for (int r = 0; r < 4; ++r) bb[c][r] = qb0[r] + kq[c];
    }
    __syncthreads(); // #2: staging visible

    // ---- c2c + bias + scale + mask ----
    f32x4 s[4];
    #pragma unroll
    for (int c = 0; c < 4; ++c) {
      short8 kb0 = swz8(&smem[KsO], c * 16 + l15, lg);
      short8 kb1 = swz8(&smem[KsO], c * 16 + l15, 4 + lg);
      s[c] = mfma16(aq1, kb1, mfma16(aq0, kb0, Z));
      #pragma unroll
      for (int r = 0; r < 4; ++r) {
        float v = (s[c][r] + bb[c][r]) * SM_SCALE;
        if (dt == 0) {
          int ql = wv * 16 + lg * 4 + r, kl = c * 16 + l15;
          if (ql < kl) v = -INFINITY;
        }
        s[c][r] = v;
      }
    }
    // ---- online softmax ----
    float alpha[4];
    #pragma unroll
    for (int r = 0; r < 4; ++r) {
      float mx = fmaxf(fmaxf(s[0][r], s[1][r]), fmaxf(s[2][r], s[3][r]));
      mx = fmaxf(mx, __shfl_xor(mx, 1));
      mx = fmaxf(mx, __shfl_xor(mx, 2));
      mx = fmaxf(mx, __shfl_xor(mx, 4));
      mx = fmaxf(mx, __shfl_xor(mx, 8));
      float mn = fmaxf(m_[r], mx);
      alpha[r] = __expf(m_[r] - mn);
      float ps = 0.f;
      #pragma unroll
      for (int c = 0; c < 4; ++c) {
        float p = __expf(s[c][r] - mn);
        s[c][r] = p;
        ps += p;
      }
      ps += __shfl_xor(ps, 1);
      ps += __shfl_xor(ps, 2);
      ps += __shfl_xor(ps, 4);
      ps += __shfl_xor(ps, 8);
      l_[r] = l_[r] * alpha[r] + ps;
      m_[r] = mn;
    }
    // ---- P -> Ps (wave-local rows; no cross-wave barrier needed) ----
    #pragma unroll
    for (int c = 0; c < 4; ++c) {
      #pragma unroll
      for (int r = 0; r < 4; ++r) {
        smem[PsO + (wv * 16 + lg * 4 + r) * 72 + c * 16 + l15] = f2b(s[c][r]);
        o[c][r] *= alpha[r];
      }
    }
    short8 ap0 = *reinterpret_cast<const short8*>(&smem[PsO + (wv * 16 + l15) * 72 + lg * 8]);
    short8 ap1 = *reinterpret_cast<const short8*>(&smem[PsO + (wv * 16 + l15) * 72 + 32 + lg * 8]);
    #pragma unroll
    for (int c = 0; c < 4; ++c) {
      short8 vb0 = *reinterpret_cast<const short8*>(&smem[VtO + (c * 16 + l15) * 72 + lg * 8]);
      short8 vb1 = *reinterpret_cast<const short8*>(&smem[VtO + (c * 16 + l15) * 72 + 32 + lg * 8]);
      o[c] = mfma16(ap1, vb1, mfma16(ap0, vb0, o[c]));
    }
  }
  #pragma unroll
  for (int r = 0; r < 4; ++r) l_[r] = 1.0f / l_[r];
  #pragma unroll
  for (int c = 0; c < 4; ++c) {
    #pragma unroll
    for (int r = 0; r < 4; ++r) {
      size_t ob = (size_t)(b * SEQ + qs + lg * 4 + r) * HID + hoff + c * 16 + l15;
      ATT[ob] = f2b(o[c][r] * l_[r]);
    }
  }
}

extern "C" void kernel_launch(void* const* d_in, const int* in_sizes, int n_in,
                              void* d_out, int out_size, void* d_ws, size_t ws_size,
                              hipStream_t stream) {
  const float* x      = (const float*)d_in[0];
  const float* Wq     = (const float*)d_in[1];
  const float* bq     = (const float*)d_in[2];
  const float* Wk     = (const float*)d_in[3];
  const float* bk     = (const float*)d_in[4];
  const float* Wv     = (const float*)d_in[5];
  const float* bv     = (const float*)d_in[6];
  const float* Wo     = (const float*)d_in[7];
  const float* bo     = (const float*)d_in[8];
  const float* relpos = (const float*)d_in[9];
  const float* gamma  = (const float*)d_in[10];
  const float* beta   = (const float*)d_in[11];
  const float* Wrk    = (const float*)d_in[12];
  const float* brk    = (const float*)d_in[13];
  const float* Wrq    = (const float*)d_in[14];
  const float* brq    = (const float*)d_in[15];
  float* out = (float*)d_out;

  u16* wsu = (u16*)d_ws;
  size_t off = 0;
  auto alloc = [&](size_t n) { u16* p = wsu + off; off += n; return p; };
  u16* xb   = alloc(4194304);
  u16* Eb   = alloc(524288);
  u16* WtQ  = alloc(1048576);
  u16* WtK  = alloc(1048576);
  u16* WtV  = alloc(1048576);
  u16* WtO  = alloc(1048576);
  u16* WtRK = alloc(1048576);
  u16* WtRQ = alloc(1048576);
  u16* Qb2  = alloc(4194304);
  u16* Kb2  = alloc(4194304);
  u16* Vb2  = alloc(4194304);
  u16* ATTb = alloc(4194304);
  u16* RKb2 = alloc(524288);
  u16* RQb2 = alloc(524288);
  float* qrk0 = (float*)(wsu + off); off += 131072;
  float* krq0 = (float*)(wsu + off); off += 131072;
  u16* band = alloc(33554432); // [2*16*2048 rows][512 d] bf16 = 67 MB

  ln_kernel<<<512, 256, 0, stream>>>(relpos, gamma, beta, Eb);
  conv_bf16<<<2048, 256, 0, stream>>>(x, xb, 4194304);
  P6 p6;
  p6.s[0] = Wq; p6.s[1] = Wk; p6.s[2] = Wv; p6.s[3] = Wo; p6.s[4] = Wrk; p6.s[5] = Wrq;
  p6.d[0] = WtQ; p6.d[1] = WtK; p6.d[2] = WtV; p6.d[3] = WtO; p6.d[4] = WtRK; p6.d[5] = WtRQ;
  dim3 gT(32, 32, 6);
  transp_all<<<gT, 256, 0, stream>>>(p6);

  dim3 gBig(8, 32);
  gemm_bf16<false><<<gBig, 256, 0, stream>>>(xb, WtQ, bq, Qb2);
  gemm_bf16<false><<<gBig, 256, 0, stream>>>(xb, WtK, bk, Kb2);
  gemm_bf16<false><<<gBig, 256, 0, stream>>>(xb, WtV, bv, Vb2);
  dim3 gRel(8, 4);
  gemm_bf16<false><<<gRel, 256, 0, stream>>>(Eb, WtRK, brk, RKb2);
  gemm_bf16<false><<<gRel, 256, 0, stream>>>(Eb, WtRQ, brq, RQb2);

  biasqk<<<1024, 256, 0, stream>>>(Qb2, Kb2, RKb2, RQb2, qrk0, krq0);

  dim3 gB(32, NH, NB);
  bias_kernel<<<gB, 256, 0, stream>>>(Qb2, Kb2, RKb2, RQb2, band);

  attn_mfma<<<gB, 256, 0, stream>>>(Qb2, Kb2, Vb2, qrk0, krq0, band, ATTb);

  gemm_bf16<true><<<gBig, 256, 0, stream>>>(ATTb, WtO, bo, out);
}

// Round 7
// 367.730 us; speedup vs baseline: 1.1259x; 1.1259x over previous
//
#include <hip/hip_runtime.h>
#include <math.h>

#define NH 16
#define HD 64
#define HID 1024
#define SEQ 2048
#define NB 2

typedef __attribute__((ext_vector_type(8))) short short8;
typedef __attribute__((ext_vector_type(4))) float f32x4;
typedef unsigned short u16;
typedef unsigned int u32;

constexpr float LN_EPS_C = 1e-5f;
constexpr float SM_SCALE = 0.07216878364870323f; // 1/sqrt(64*3)

__device__ inline u16 f2b(float f) {
  unsigned u = __builtin_bit_cast(unsigned, f);
  u = (u + 0x7FFFu + ((u >> 16) & 1u)) >> 16;
  return (u16)u;
}
__device__ inline float b2f(u16 h) {
  unsigned u = ((unsigned)h) << 16;
  return __builtin_bit_cast(float, u);
}
__device__ inline u32 pk2(float lo, float hi) {
  return (u32)f2b(lo) | ((u32)f2b(hi) << 16);
}
__device__ inline f32x4 mfma16(short8 a, short8 b, f32x4 c) {
  return __builtin_amdgcn_mfma_f32_16x16x32_bf16(a, b, c, 0, 0, 0);
}
// swizzled read of a [rows][64] bf16 tile whose writes used slot = chunk^(row&7)
__device__ inline short8 swz8(const u16* base, int row, int hc) {
  return *reinterpret_cast<const short8*>(&base[row * 64 + 8 * (hc ^ (row & 7))]);
}
// add-rotate swizzle for [64 row][72-stride] tiles, col in [0,64).
// Preserves 8-aligned col-block contiguity; conflict-free writes, 2-way reads.
__device__ inline int vrot(int row, int col) {
  return row * 72 + ((col + 16 * ((row >> 3) & 3)) & 63);
}

// ---------------- LayerNorm over relpos_table rows -> bf16 ----------------
__global__ __launch_bounds__(256) void ln_kernel(const float* __restrict__ tbl,
    const float* __restrict__ gamma, const float* __restrict__ beta,
    u16* __restrict__ e) {
  int row = blockIdx.x;
  int t = threadIdx.x;
  const float4* rp = reinterpret_cast<const float4*>(tbl + (size_t)row * HID);
  float4 x = rp[t];
  float s = x.x + x.y + x.z + x.w;
  float ss = x.x * x.x + x.y * x.y + x.z * x.z + x.w * x.w;
  #pragma unroll
  for (int o = 1; o < 64; o <<= 1) {
    s += __shfl_xor(s, o);
    ss += __shfl_xor(ss, o);
  }
  __shared__ float sb[4], ssb[4];
  int w = t >> 6;
  if ((t & 63) == 0) { sb[w] = s; ssb[w] = ss; }
  __syncthreads();
  s = sb[0] + sb[1] + sb[2] + sb[3];
  ss = ssb[0] + ssb[1] + ssb[2] + ssb[3];
  float mu = s * (1.0f / HID);
  float var = ss * (1.0f / HID) - mu * mu;
  float rs = rsqrtf(var + LN_EPS_C);
  float4 g = reinterpret_cast<const float4*>(gamma)[t];
  float4 bt = reinterpret_cast<const float4*>(beta)[t];
  ushort4 o4;
  o4.x = f2b((x.x - mu) * rs * g.x + bt.x);
  o4.y = f2b((x.y - mu) * rs * g.y + bt.y);
  o4.z = f2b((x.z - mu) * rs * g.z + bt.z);
  o4.w = f2b((x.w - mu) * rs * g.w + bt.w);
  *reinterpret_cast<ushort4*>(&e[(size_t)row * HID + t * 4]) = o4;
}

// ---------------- f32 -> bf16 convert ----------------
__global__ __launch_bounds__(256) void conv_bf16(const float* __restrict__ src,
    u16* __restrict__ dst, int n) {
  int i = (blockIdx.x * 256 + threadIdx.x) * 8;
  if (i >= n) return;
  float4 a = *reinterpret_cast<const float4*>(&src[i]);
  float4 c = *reinterpret_cast<const float4*>(&src[i + 4]);
  short8 o;
  o[0] = (short)f2b(a.x); o[1] = (short)f2b(a.y); o[2] = (short)f2b(a.z); o[3] = (short)f2b(a.w);
  o[4] = (short)f2b(c.x); o[5] = (short)f2b(c.y); o[6] = (short)f2b(c.z); o[7] = (short)f2b(c.w);
  *reinterpret_cast<short8*>(&dst[i]) = o;
}

// ---------------- all 6 weight transposes in one launch ----------------
struct P6 {
  const float* s[6];
  u16* d[6];
};
__global__ __launch_bounds__(256) void transp_all(P6 p) {
  __shared__ float T[32][33];
  const float* W = p.s[blockIdx.z];
  u16* Wt = p.d[blockIdx.z];
  int bn = blockIdx.x * 32, bk = blockIdx.y * 32;
  int t = threadIdx.x;
  int r = t >> 3, c4 = (t & 7) * 4;
  float4 v = *reinterpret_cast<const float4*>(&W[(size_t)(bk + r) * HID + bn + c4]);
  T[r][c4 + 0] = v.x; T[r][c4 + 1] = v.y; T[r][c4 + 2] = v.z; T[r][c4 + 3] = v.w;
  __syncthreads();
  int n = t >> 3, k4 = (t & 7) * 4;
  ushort4 o;
  o.x = f2b(T[k4 + 0][n]); o.y = f2b(T[k4 + 1][n]);
  o.z = f2b(T[k4 + 2][n]); o.w = f2b(T[k4 + 3][n]);
  *reinterpret_cast<ushort4*>(&Wt[(size_t)(bn + n) * HID + bk + k4]) = o;
}

// ---------------- bf16 MFMA GEMM: BK=64, write-XOR swizzle staging, reg prefetch ----------------
template <bool F32OUT>
__global__ __launch_bounds__(256) void gemm_bf16(const u16* __restrict__ A,
    const u16* __restrict__ Bt, const float* __restrict__ bias,
    void* __restrict__ Cout) {
  __shared__ u16 Al[8192]; // [128][64] swizzled
  __shared__ u16 Bl[8192];
  int t = threadIdx.x;
  int cb = blockIdx.x * 128, rb = blockIdx.y * 128;
  int wv = t >> 6, lane = t & 63, l15 = lane & 15, lg = lane >> 4;
  int wr = (wv >> 1) * 64, wc = (wv & 1) * 64;
  int srow = t >> 1, scb = (t & 1) * 4;
  f32x4 acc[4][4];
  #pragma unroll
  for (int i = 0; i < 4; ++i)
    #pragma unroll
    for (int j = 0; j < 4; ++j) acc[i][j] = (f32x4){0.f, 0.f, 0.f, 0.f};
  const u16* Ap = A + (size_t)(rb + srow) * HID;
  const u16* Bp = Bt + (size_t)(cb + srow) * HID;
  short8 pa[4], pb[4];
  #pragma unroll
  for (int c4 = 0; c4 < 4; ++c4) {
    pa[c4] = *reinterpret_cast<const short8*>(&Ap[(scb + c4) * 8]);
    pb[c4] = *reinterpret_cast<const short8*>(&Bp[(scb + c4) * 8]);
  }
  for (int kk = 0; kk < HID; kk += 64) {
    __syncthreads();
    #pragma unroll
    for (int c4 = 0; c4 < 4; ++c4) {
      int slot = 8 * ((scb + c4) ^ (srow & 7));
      *reinterpret_cast<short8*>(&Al[srow * 64 + slot]) = pa[c4];
      *reinterpret_cast<short8*>(&Bl[srow * 64 + slot]) = pb[c4];
    }
    __syncthreads();
    if (kk + 64 < HID) {
      #pragma unroll
      for (int c4 = 0; c4 < 4; ++c4) {
        pa[c4] = *reinterpret_cast<const short8*>(&Ap[kk + 64 + (scb + c4) * 8]);
        pb[c4] = *reinterpret_cast<const short8*>(&Bp[kk + 64 + (scb + c4) * 8]);
      }
    }
    #pragma unroll
    for (int s = 0; s < 2; ++s) {
      short8 am[4], bn[4];
      #pragma unroll
      for (int i = 0; i < 4; ++i) am[i] = swz8(Al, wr + i * 16 + l15, s * 4 + lg);
      #pragma unroll
      for (int j = 0; j < 4; ++j) bn[j] = swz8(Bl, wc + j * 16 + l15, s * 4 + lg);
      #pragma unroll
      for (int i = 0; i < 4; ++i)
        #pragma unroll
        for (int j = 0; j < 4; ++j)
          acc[i][j] = mfma16(am[i], bn[j], acc[i][j]);
    }
  }
  #pragma unroll
  for (int j = 0; j < 4; ++j) {
    float bv = bias[cb + wc + j * 16 + l15];
    #pragma unroll
    for (int i = 0; i < 4; ++i) {
      #pragma unroll
      for (int r = 0; r < 4; ++r) {
        size_t idx = (size_t)(rb + wr + i * 16 + lg * 4 + r) * HID + cb + wc + j * 16 + l15;
        float v = acc[i][j][r] + bv;
        if (F32OUT) reinterpret_cast<float*>(Cout)[idx] = v;
        else reinterpret_cast<u16*>(Cout)[idx] = f2b(v);
      }
    }
  }
}

// ---------------- rank-1 bias precompute: qrk0 = Q.rk[0], krq0 = K.rq[0] ----------------
__global__ __launch_bounds__(256) void biasqk(const u16* __restrict__ Qb,
    const u16* __restrict__ Kb, const u16* __restrict__ RKb,
    const u16* __restrict__ RQb, float* __restrict__ qrk0,
    float* __restrict__ krq0) {
  int o = blockIdx.x * 64 + (threadIdx.x >> 2);
  int sub = threadIdx.x & 3;
  int b = o >> 15, h = (o >> 11) & 15, i = o & 2047;
  size_t rbase = (size_t)(b * SEQ + i) * HID + h * HD + sub * 16;
  size_t tbase = (size_t)h * HD + sub * 16;
  float s1 = 0.f, s2 = 0.f;
  #pragma unroll
  for (int c = 0; c < 2; ++c) {
    short8 qv = *reinterpret_cast<const short8*>(&Qb[rbase + c * 8]);
    short8 rv = *reinterpret_cast<const short8*>(&RKb[tbase + c * 8]);
    short8 kv = *reinterpret_cast<const short8*>(&Kb[rbase + c * 8]);
    short8 uv = *reinterpret_cast<const short8*>(&RQb[tbase + c * 8]);
    #pragma unroll
    for (int j = 0; j < 8; ++j) {
      s1 += b2f((u16)qv[j]) * b2f((u16)rv[j]);
      s2 += b2f((u16)kv[j]) * b2f((u16)uv[j]);
    }
  }
  s1 += __shfl_xor(s1, 1); s1 += __shfl_xor(s1, 2);
  s2 += __shfl_xor(s2, 1); s2 += __shfl_xor(s2, 2);
  if (sub == 0) { qrk0[o] = s1; krq0[o] = s2; }
}

// ---------------- band bias precompute (validated G machinery) ----------------
// band[(bh + q)*512 + d] = Q[q].rk[511-d] + K[q-d].rq[511-d],  d in [0,511]
__global__ __launch_bounds__(256, 3) void bias_kernel(
    const u16* __restrict__ Qb, const u16* __restrict__ Kb,
    const u16* __restrict__ RKb, const u16* __restrict__ RQb,
    u16* __restrict__ band) {
  __shared__ u16 smem[20992]; // 41984 B -> 3 blocks/CU
  const int KsO = 0, UO = 4096;
  const int RKO = UO, RQO = UO + 8192;
  const int G1O = UO, G2O = UO + 8448;

  int qt = blockIdx.x;
  int h = blockIdx.y, b = blockIdx.z;
  int q0 = qt * 64;
  int t = threadIdx.x;
  int wv = t >> 6, lane = t & 63, l15 = lane & 15, lg = lane >> 4;
  int qs = q0 + wv * 16;
  int hoff = h * HD;
  int bh = (b * NH + h) * SEQ;

  size_t qgrow = (size_t)(b * SEQ + qs + l15) * HID + hoff;
  short8 aq0 = *reinterpret_cast<const short8*>(&Qb[qgrow + lg * 8]);
  short8 aq1 = *reinterpret_cast<const short8*>(&Qb[qgrow + 32 + lg * 8]);

  const f32x4 Z = (f32x4){0.f, 0.f, 0.f, 0.f};
  int vr = t >> 2, vc8 = (t & 3) * 8;
  int ktlo = qt - 8; if (ktlo < 0) ktlo = 0;

  for (int kt = ktlo; kt <= qt; ++kt) {
    int k0 = kt * 64;
    int dt = qt - kt;
    int wlo = 448 - 64 * dt; if (wlo < 0) wlo = 0;
    __syncthreads(); // #1: previous iteration's gathers done
    {
      const u16* kg = &Kb[(size_t)(b * SEQ + k0 + vr) * HID + hoff];
      int c0 = vc8 >> 3;
      *reinterpret_cast<short8*>(&smem[KsO + vr * 64 + 8 * (c0 ^ (vr & 7))]) =
          *reinterpret_cast<const short8*>(&kg[vc8]);
      *reinterpret_cast<short8*>(&smem[KsO + vr * 64 + 8 * ((c0 + 4) ^ (vr & 7))]) =
          *reinterpret_cast<const short8*>(&kg[vc8 + 32]);
    }
    for (int e2 = t; e2 < 1024; e2 += 256) {
      int rr = e2 >> 3, cch = e2 & 7;
      int wr2 = wlo + rr; if (wr2 > 511) wr2 = 511;
      size_t gb = (size_t)wr2 * HID + hoff + cch * 8;
      int slot = 8 * (cch ^ (rr & 7));
      *reinterpret_cast<short8*>(&smem[RKO + rr * 64 + slot]) =
          *reinterpret_cast<const short8*>(&RKb[gb]);
      *reinterpret_cast<short8*>(&smem[RQO + rr * 64 + slot]) =
          *reinterpret_cast<const short8*>(&RQb[gb]);
    }
    __syncthreads(); // #2: staging visible
    u32 g1p[16], g2p[16];
    #pragma unroll
    for (int cw = 0; cw < 8; ++cw) {
      short8 r0 = swz8(&smem[RKO], cw * 16 + l15, lg);
      short8 r1 = swz8(&smem[RKO], cw * 16 + l15, 4 + lg);
      f32x4 g = mfma16(r1, aq1, mfma16(r0, aq0, Z));
      g1p[2 * cw] = pk2(g[0], g[1]);
      g1p[2 * cw + 1] = pk2(g[2], g[3]);
    }
    short8 kw0 = swz8(&smem[KsO], wv * 16 + l15, lg);
    short8 kw1 = swz8(&smem[KsO], wv * 16 + l15, 4 + lg);
    #pragma unroll
    for (int cw = 0; cw < 8; ++cw) {
      short8 u0 = swz8(&smem[RQO], cw * 16 + l15, lg);
      short8 u1 = swz8(&smem[RQO], cw * 16 + l15, 4 + lg);
      f32x4 g = mfma16(u1, kw1, mfma16(u0, kw0, Z));
      g2p[2 * cw] = pk2(g[0], g[1]);
      g2p[2 * cw + 1] = pk2(g[2], g[3]);
    }
    __syncthreads(); // #3: band reads done; U reusable for G
    #pragma unroll
    for (int cw = 0; cw < 8; ++cw) {
      *reinterpret_cast<uint2*>(&smem[G1O + (wv * 16 + l15) * 132 + cw * 16 + lg * 4]) =
          make_uint2(g1p[2 * cw], g1p[2 * cw + 1]);
      *reinterpret_cast<uint2*>(&smem[G2O + (wv * 16 + l15) * 132 + cw * 16 + lg * 4]) =
          make_uint2(g2p[2 * cw], g2p[2 * cw + 1]);
    }
    __syncthreads(); // #4: G visible
    #pragma unroll
    for (int c = 0; c < 4; ++c) {
      #pragma unroll
      for (int r = 0; r < 4; ++r) {
        int q = qs + lg * 4 + r;
        int k = k0 + c * 16 + l15;
        int d = q - k;
        int wi = 511 - d - wlo; if (wi < 0) wi = 0;
        float v = b2f(smem[G1O + (wv * 16 + lg * 4 + r) * 132 + wi]) +
                  b2f(smem[G2O + (c * 16 + l15) * 132 + wi]);
        if (d >= 0 && d < 512)
          band[((size_t)(bh + q) << 9) + d] = f2b(v);
      }
    }
  }
}

// ---------------- fused DeBERTa flash attention: dbuf K/V, 1 barrier/tile ----------------
// LDS (u16): Ks0 @0, Ks1 @4096 ([64][64] XOR-swz); Vt0 @8192, Vt1 @12800
// ([64 d][72] add-rotate); Ps @17408 ([64 q][72] add-rotate). 44032 B.
__global__ __launch_bounds__(256, 3) void attn_mfma(
    const u16* __restrict__ Qb, const u16* __restrict__ Kb,
    const u16* __restrict__ Vb, const float* __restrict__ qrk0,
    const float* __restrict__ krq0, const u16* __restrict__ band,
    u16* __restrict__ ATT) {
  __shared__ u16 smem[22016];
  const int KsB[2] = {0, 4096};
  const int VtB[2] = {8192, 12800};
  const int PsO = 17408;

  int qt = (int)gridDim.x - 1 - (int)blockIdx.x; // heavy tiles first
  int h = blockIdx.y, b = blockIdx.z;
  int q0 = qt * 64;
  int t = threadIdx.x;
  int wv = t >> 6, lane = t & 63, l15 = lane & 15, lg = lane >> 4;
  int qs = q0 + wv * 16;
  int hoff = h * HD;
  int bh = (b * NH + h) * SEQ;
  const u16* bandq = band + ((size_t)bh << 9);

  size_t qgrow = (size_t)(b * SEQ + qs + l15) * HID + hoff;
  short8 aq0 = *reinterpret_cast<const short8*>(&Qb[qgrow + lg * 8]);
  short8 aq1 = *reinterpret_cast<const short8*>(&Qb[qgrow + 32 + lg * 8]);
  float qb0[4];
  #pragma unroll
  for (int r = 0; r < 4; ++r) qb0[r] = qrk0[bh + qs + lg * 4 + r];

  float m_[4], l_[4];
  f32x4 o[4];
  #pragma unroll
  for (int r = 0; r < 4; ++r) { m_[r] = -INFINITY; l_[r] = 0.f; }
  #pragma unroll
  for (int c = 0; c < 4; ++c) o[c] = (f32x4){0.f, 0.f, 0.f, 0.f};

  const f32x4 Z = (f32x4){0.f, 0.f, 0.f, 0.f};
  int vr = t >> 2, vc8 = (t & 3) * 8;
  int c0s = vc8 >> 3;

  // ---- prologue: stage tile 0 into buffer 0 ----
  {
    const u16* kg = &Kb[(size_t)(b * SEQ + vr) * HID + hoff];
    short8 k0v = *reinterpret_cast<const short8*>(&kg[vc8]);
    short8 k1v = *reinterpret_cast<const short8*>(&kg[vc8 + 32]);
    *reinterpret_cast<short8*>(&smem[KsB[0] + vr * 64 + 8 * (c0s ^ (vr & 7))]) = k0v;
    *reinterpret_cast<short8*>(&smem[KsB[0] + vr * 64 + 8 * ((c0s + 4) ^ (vr & 7))]) = k1v;
    const u16* vg = &Vb[(size_t)(b * SEQ + vr) * HID + hoff];
    short8 v0v = *reinterpret_cast<const short8*>(&vg[vc8]);
    short8 v1v = *reinterpret_cast<const short8*>(&vg[vc8 + 32]);
    #pragma unroll
    for (int j = 0; j < 8; ++j) smem[VtB[0] + vrot(vc8 + j, vr)] = (u16)v0v[j];
    #pragma unroll
    for (int j = 0; j < 8; ++j) smem[VtB[0] + vrot(vc8 + 32 + j, vr)] = (u16)v1v[j];
  }
  __syncthreads();

  int cur = 0;
  for (int kt = 0; kt <= qt; ++kt) {
    int k0 = kt * 64;
    int dt = qt - kt;
    bool banded = (dt <= 8);
    int ksb = KsB[cur], vtb = VtB[cur];
    int ksn = KsB[cur ^ 1], vtn = VtB[cur ^ 1];

    // ---- early: bias loads (clamped addr; selected later) ----
    float kq[4];
    #pragma unroll
    for (int c = 0; c < 4; ++c) kq[c] = krq0[bh + k0 + c * 16 + l15];
    u16 braw[4][4];
    if (banded) {
      #pragma unroll
      for (int c = 0; c < 4; ++c) {
        #pragma unroll
        for (int r = 0; r < 4; ++r) {
          int q = qs + lg * 4 + r;
          int d = q - (k0 + c * 16 + l15);
          int dc = d < 0 ? 0 : (d > 511 ? 511 : d);
          braw[c][r] = bandq[((size_t)q << 9) + dc];
        }
      }
    }
    // ---- early: prefetch next K/V tile to registers ----
    short8 nk0, nk1, nv0, nv1;
    if (kt < qt) {
      const u16* kg = &Kb[(size_t)(b * SEQ + k0 + 64 + vr) * HID + hoff];
      nk0 = *reinterpret_cast<const short8*>(&kg[vc8]);
      nk1 = *reinterpret_cast<const short8*>(&kg[vc8 + 32]);
      const u16* vg = &Vb[(size_t)(b * SEQ + k0 + 64 + vr) * HID + hoff];
      nv0 = *reinterpret_cast<const short8*>(&vg[vc8]);
      nv1 = *reinterpret_cast<const short8*>(&vg[vc8 + 32]);
    }

    // ---- c2c ----
    f32x4 s[4];
    #pragma unroll
    for (int c = 0; c < 4; ++c) {
      short8 kb0 = swz8(&smem[ksb], c * 16 + l15, lg);
      short8 kb1 = swz8(&smem[ksb], c * 16 + l15, 4 + lg);
      s[c] = mfma16(aq1, kb1, mfma16(aq0, kb0, Z));
    }
    // ---- bias + scale + mask ----
    #pragma unroll
    for (int c = 0; c < 4; ++c) {
      #pragma unroll
      for (int r = 0; r < 4; ++r) {
        float bbv;
        if (banded) {
          int q = qs + lg * 4 + r;
          int d = q - (k0 + c * 16 + l15);
          bbv = (d >= 0 && d < 512) ? b2f(braw[c][r]) : qb0[r] + kq[c];
        } else {
          bbv = qb0[r] + kq[c];
        }
        float v = (s[c][r] + bbv) * SM_SCALE;
        if (dt == 0) {
          int ql = wv * 16 + lg * 4 + r, kl = c * 16 + l15;
          if (ql < kl) v = -INFINITY;
        }
        s[c][r] = v;
      }
    }
    // ---- online softmax ----
    float alpha[4];
    #pragma unroll
    for (int r = 0; r < 4; ++r) {
      float mx = fmaxf(fmaxf(s[0][r], s[1][r]), fmaxf(s[2][r], s[3][r]));
      mx = fmaxf(mx, __shfl_xor(mx, 1));
      mx = fmaxf(mx, __shfl_xor(mx, 2));
      mx = fmaxf(mx, __shfl_xor(mx, 4));
      mx = fmaxf(mx, __shfl_xor(mx, 8));
      float mn = fmaxf(m_[r], mx);
      alpha[r] = __expf(m_[r] - mn);
      float ps = 0.f;
      #pragma unroll
      for (int c = 0; c < 4; ++c) {
        float p = __expf(s[c][r] - mn);
        s[c][r] = p;
        ps += p;
      }
      ps += __shfl_xor(ps, 1);
      ps += __shfl_xor(ps, 2);
      ps += __shfl_xor(ps, 4);
      ps += __shfl_xor(ps, 8);
      l_[r] = l_[r] * alpha[r] + ps;
      m_[r] = mn;
    }
    // ---- P -> Ps (add-rotate; wave-local rows), rescale O ----
    #pragma unroll
    for (int c = 0; c < 4; ++c) {
      #pragma unroll
      for (int r = 0; r < 4; ++r) {
        smem[PsO + vrot(wv * 16 + lg * 4 + r, c * 16 + l15)] = f2b(s[c][r]);
        o[c][r] *= alpha[r];
      }
    }
    int prow = wv * 16 + l15;
    short8 ap0 = *reinterpret_cast<const short8*>(&smem[PsO + vrot(prow, lg * 8)]);
    short8 ap1 = *reinterpret_cast<const short8*>(&smem[PsO + vrot(prow, 32 + lg * 8)]);
    // ---- PV ----
    #pragma unroll
    for (int c = 0; c < 4; ++c) {
      int n = c * 16 + l15;
      short8 vb0 = *reinterpret_cast<const short8*>(&smem[vtb + vrot(n, lg * 8)]);
      short8 vb1 = *reinterpret_cast<const short8*>(&smem[vtb + vrot(n, 32 + lg * 8)]);
      o[c] = mfma16(ap1, vb1, mfma16(ap0, vb0, o[c]));
    }
    // ---- write prefetched tile into the other buffer ----
    if (kt < qt) {
      *reinterpret_cast<short8*>(&smem[ksn + vr * 64 + 8 * (c0s ^ (vr & 7))]) = nk0;
      *reinterpret_cast<short8*>(&smem[ksn + vr * 64 + 8 * ((c0s + 4) ^ (vr & 7))]) = nk1;
      #pragma unroll
      for (int j = 0; j < 8; ++j) smem[vtn + vrot(vc8 + j, vr)] = (u16)nv0[j];
      #pragma unroll
      for (int j = 0; j < 8; ++j) smem[vtn + vrot(vc8 + 32 + j, vr)] = (u16)nv1[j];
    }
    __syncthreads(); // single barrier per tile
    cur ^= 1;
  }
  #pragma unroll
  for (int r = 0; r < 4; ++r) l_[r] = 1.0f / l_[r];
  #pragma unroll
  for (int c = 0; c < 4; ++c) {
    #pragma unroll
    for (int r = 0; r < 4; ++r) {
      size_t ob = (size_t)(b * SEQ + qs + lg * 4 + r) * HID + hoff + c * 16 + l15;
      ATT[ob] = f2b(o[c][r] * l_[r]);
    }
  }
}

extern "C" void kernel_launch(void* const* d_in, const int* in_sizes, int n_in,
                              void* d_out, int out_size, void* d_ws, size_t ws_size,
                              hipStream_t stream) {
  const float* x      = (const float*)d_in[0];
  const float* Wq     = (const float*)d_in[1];
  const float* bq     = (const float*)d_in[2];
  const float* Wk     = (const float*)d_in[3];
  const float* bk     = (const float*)d_in[4];
  const float* Wv     = (const float*)d_in[5];
  const float* bv     = (const float*)d_in[6];
  const float* Wo     = (const float*)d_in[7];
  const float* bo     = (const float*)d_in[8];
  const float* relpos = (const float*)d_in[9];
  const float* gamma  = (const float*)d_in[10];
  const float* beta   = (const float*)d_in[11];
  const float* Wrk    = (const float*)d_in[12];
  const float* brk    = (const float*)d_in[13];
  const float* Wrq    = (const float*)d_in[14];
  const float* brq    = (const float*)d_in[15];
  float* out = (float*)d_out;

  u16* wsu = (u16*)d_ws;
  size_t off = 0;
  auto alloc = [&](size_t n) { u16* p = wsu + off; off += n; return p; };
  u16* xb   = alloc(4194304);
  u16* Eb   = alloc(524288);
  u16* WtQ  = alloc(1048576);
  u16* WtK  = alloc(1048576);
  u16* WtV  = alloc(1048576);
  u16* WtO  = alloc(1048576);
  u16* WtRK = alloc(1048576);
  u16* WtRQ = alloc(1048576);
  u16* Qb2  = alloc(4194304);
  u16* Kb2  = alloc(4194304);
  u16* Vb2  = alloc(4194304);
  u16* ATTb = alloc(4194304);
  u16* RKb2 = alloc(524288);
  u16* RQb2 = alloc(524288);
  float* qrk0 = (float*)(wsu + off); off += 131072;
  float* krq0 = (float*)(wsu + off); off += 131072;
  u16* band = alloc(33554432); // [2*16*2048 rows][512 d] bf16 = 67 MB

  ln_kernel<<<512, 256, 0, stream>>>(relpos, gamma, beta, Eb);
  conv_bf16<<<2048, 256, 0, stream>>>(x, xb, 4194304);
  P6 p6;
  p6.s[0] = Wq; p6.s[1] = Wk; p6.s[2] = Wv; p6.s[3] = Wo; p6.s[4] = Wrk; p6.s[5] = Wrq;
  p6.d[0] = WtQ; p6.d[1] = WtK; p6.d[2] = WtV; p6.d[3] = WtO; p6.d[4] = WtRK; p6.d[5] = WtRQ;
  dim3 gT(32, 32, 6);
  transp_all<<<gT, 256, 0, stream>>>(p6);

  dim3 gBig(8, 32);
  gemm_bf16<false><<<gBig, 256, 0, stream>>>(xb, WtQ, bq, Qb2);
  gemm_bf16<false><<<gBig, 256, 0, stream>>>(xb, WtK, bk, Kb2);
  gemm_bf16<false><<<gBig, 256, 0, stream>>>(xb, WtV, bv, Vb2);
  dim3 gRel(8, 4);
  gemm_bf16<false><<<gRel, 256, 0, stream>>>(Eb, WtRK, brk, RKb2);
  gemm_bf16<false><<<gRel, 256, 0, stream>>>(Eb, WtRQ, brq, RQb2);

  biasqk<<<1024, 256, 0, stream>>>(Qb2, Kb2, RKb2, RQb2, qrk0, krq0);

  dim3 gB(32, NH, NB);
  bias_kernel<<<gB, 256, 0, stream>>>(Qb2, Kb2, RKb2, RQb2, band);

  attn_mfma<<<gB, 256, 0, stream>>>(Qb2, Kb2, Vb2, qrk0, krq0, band, ATTb);

  gemm_bf16<true><<<gBig, 256, 0, stream>>>(ATTb, WtO, bo, out);
}

// Round 8
// 319.922 us; speedup vs baseline: 1.2942x; 1.1494x over previous
//
#include <hip/hip_runtime.h>
#include <math.h>

#define NH 16
#define HD 64
#define HID 1024
#define SEQ 2048
#define NB 2

typedef __attribute__((ext_vector_type(8))) short short8;
typedef __attribute__((ext_vector_type(4))) float f32x4;
typedef unsigned short u16;
typedef unsigned int u32;

constexpr float LN_EPS_C = 1e-5f;
constexpr float SM_SCALE = 0.07216878364870323f; // 1/sqrt(64*3)

__device__ inline u16 f2b(float f) {
  unsigned u = __builtin_bit_cast(unsigned, f);
  u = (u + 0x7FFFu + ((u >> 16) & 1u)) >> 16;
  return (u16)u;
}
__device__ inline float b2f(u16 h) {
  unsigned u = ((unsigned)h) << 16;
  return __builtin_bit_cast(float, u);
}
__device__ inline u32 pk2(float lo, float hi) {
  return (u32)f2b(lo) | ((u32)f2b(hi) << 16);
}
__device__ inline f32x4 mfma16(short8 a, short8 b, f32x4 c) {
  return __builtin_amdgcn_mfma_f32_16x16x32_bf16(a, b, c, 0, 0, 0);
}
// swizzled read of a [rows][64] bf16 tile whose writes used slot = chunk^(row&7)
__device__ inline short8 swz8(const u16* base, int row, int hc) {
  return *reinterpret_cast<const short8*>(&base[row * 64 + 8 * (hc ^ (row & 7))]);
}
// add-rotate swizzle for [64 row][72-stride] tiles, col in [0,64).
__device__ inline int vrot(int row, int col) {
  return row * 72 + ((col + 16 * ((row >> 3) & 3)) & 63);
}

// ---------------- LayerNorm over relpos_table rows -> bf16 ----------------
__global__ __launch_bounds__(256) void ln_kernel(const float* __restrict__ tbl,
    const float* __restrict__ gamma, const float* __restrict__ beta,
    u16* __restrict__ e) {
  int row = blockIdx.x;
  int t = threadIdx.x;
  const float4* rp = reinterpret_cast<const float4*>(tbl + (size_t)row * HID);
  float4 x = rp[t];
  float s = x.x + x.y + x.z + x.w;
  float ss = x.x * x.x + x.y * x.y + x.z * x.z + x.w * x.w;
  #pragma unroll
  for (int o = 1; o < 64; o <<= 1) {
    s += __shfl_xor(s, o);
    ss += __shfl_xor(ss, o);
  }
  __shared__ float sb[4], ssb[4];
  int w = t >> 6;
  if ((t & 63) == 0) { sb[w] = s; ssb[w] = ss; }
  __syncthreads();
  s = sb[0] + sb[1] + sb[2] + sb[3];
  ss = ssb[0] + ssb[1] + ssb[2] + ssb[3];
  float mu = s * (1.0f / HID);
  float var = ss * (1.0f / HID) - mu * mu;
  float rs = rsqrtf(var + LN_EPS_C);
  float4 g = reinterpret_cast<const float4*>(gamma)[t];
  float4 bt = reinterpret_cast<const float4*>(beta)[t];
  ushort4 o4;
  o4.x = f2b((x.x - mu) * rs * g.x + bt.x);
  o4.y = f2b((x.y - mu) * rs * g.y + bt.y);
  o4.z = f2b((x.z - mu) * rs * g.z + bt.z);
  o4.w = f2b((x.w - mu) * rs * g.w + bt.w);
  *reinterpret_cast<ushort4*>(&e[(size_t)row * HID + t * 4]) = o4;
}

// ---------------- f32 -> bf16 convert ----------------
__global__ __launch_bounds__(256) void conv_bf16(const float* __restrict__ src,
    u16* __restrict__ dst, int n) {
  int i = (blockIdx.x * 256 + threadIdx.x) * 8;
  if (i >= n) return;
  float4 a = *reinterpret_cast<const float4*>(&src[i]);
  float4 c = *reinterpret_cast<const float4*>(&src[i + 4]);
  short8 o;
  o[0] = (short)f2b(a.x); o[1] = (short)f2b(a.y); o[2] = (short)f2b(a.z); o[3] = (short)f2b(a.w);
  o[4] = (short)f2b(c.x); o[5] = (short)f2b(c.y); o[6] = (short)f2b(c.z); o[7] = (short)f2b(c.w);
  *reinterpret_cast<short8*>(&dst[i]) = o;
}

// ---------------- all 6 weight transposes in one launch ----------------
struct P6 {
  const float* s[6];
  u16* d[6];
};
__global__ __launch_bounds__(256) void transp_all(P6 p) {
  __shared__ float T[32][33];
  const float* W = p.s[blockIdx.z];
  u16* Wt = p.d[blockIdx.z];
  int bn = blockIdx.x * 32, bk = blockIdx.y * 32;
  int t = threadIdx.x;
  int r = t >> 3, c4 = (t & 7) * 4;
  float4 v = *reinterpret_cast<const float4*>(&W[(size_t)(bk + r) * HID + bn + c4]);
  T[r][c4 + 0] = v.x; T[r][c4 + 1] = v.y; T[r][c4 + 2] = v.z; T[r][c4 + 3] = v.w;
  __syncthreads();
  int n = t >> 3, k4 = (t & 7) * 4;
  ushort4 o;
  o.x = f2b(T[k4 + 0][n]); o.y = f2b(T[k4 + 1][n]);
  o.z = f2b(T[k4 + 2][n]); o.w = f2b(T[k4 + 3][n]);
  *reinterpret_cast<ushort4*>(&Wt[(size_t)(bn + n) * HID + bk + k4]) = o;
}

// ---------------- bf16 MFMA GEMM: BK=64, write-XOR swizzle staging, reg prefetch ----------------
template <bool F32OUT>
__global__ __launch_bounds__(256) void gemm_bf16(const u16* __restrict__ A,
    const u16* __restrict__ Bt, const float* __restrict__ bias,
    void* __restrict__ Cout) {
  __shared__ u16 Al[8192]; // [128][64] swizzled
  __shared__ u16 Bl[8192];
  int t = threadIdx.x;
  int cb = blockIdx.x * 128, rb = blockIdx.y * 128;
  int wv = t >> 6, lane = t & 63, l15 = lane & 15, lg = lane >> 4;
  int wr = (wv >> 1) * 64, wc = (wv & 1) * 64;
  int srow = t >> 1, scb = (t & 1) * 4;
  f32x4 acc[4][4];
  #pragma unroll
  for (int i = 0; i < 4; ++i)
    #pragma unroll
    for (int j = 0; j < 4; ++j) acc[i][j] = (f32x4){0.f, 0.f, 0.f, 0.f};
  const u16* Ap = A + (size_t)(rb + srow) * HID;
  const u16* Bp = Bt + (size_t)(cb + srow) * HID;
  short8 pa[4], pb[4];
  #pragma unroll
  for (int c4 = 0; c4 < 4; ++c4) {
    pa[c4] = *reinterpret_cast<const short8*>(&Ap[(scb + c4) * 8]);
    pb[c4] = *reinterpret_cast<const short8*>(&Bp[(scb + c4) * 8]);
  }
  for (int kk = 0; kk < HID; kk += 64) {
    __syncthreads();
    #pragma unroll
    for (int c4 = 0; c4 < 4; ++c4) {
      int slot = 8 * ((scb + c4) ^ (srow & 7));
      *reinterpret_cast<short8*>(&Al[srow * 64 + slot]) = pa[c4];
      *reinterpret_cast<short8*>(&Bl[srow * 64 + slot]) = pb[c4];
    }
    __syncthreads();
    if (kk + 64 < HID) {
      #pragma unroll
      for (int c4 = 0; c4 < 4; ++c4) {
        pa[c4] = *reinterpret_cast<const short8*>(&Ap[kk + 64 + (scb + c4) * 8]);
        pb[c4] = *reinterpret_cast<const short8*>(&Bp[kk + 64 + (scb + c4) * 8]);
      }
    }
    #pragma unroll
    for (int s = 0; s < 2; ++s) {
      short8 am[4], bn[4];
      #pragma unroll
      for (int i = 0; i < 4; ++i) am[i] = swz8(Al, wr + i * 16 + l15, s * 4 + lg);
      #pragma unroll
      for (int j = 0; j < 4; ++j) bn[j] = swz8(Bl, wc + j * 16 + l15, s * 4 + lg);
      #pragma unroll
      for (int i = 0; i < 4; ++i)
        #pragma unroll
        for (int j = 0; j < 4; ++j)
          acc[i][j] = mfma16(am[i], bn[j], acc[i][j]);
    }
  }
  #pragma unroll
  for (int j = 0; j < 4; ++j) {
    float bv = bias[cb + wc + j * 16 + l15];
    #pragma unroll
    for (int i = 0; i < 4; ++i) {
      #pragma unroll
      for (int r = 0; r < 4; ++r) {
        size_t idx = (size_t)(rb + wr + i * 16 + lg * 4 + r) * HID + cb + wc + j * 16 + l15;
        float v = acc[i][j][r] + bv;
        if (F32OUT) reinterpret_cast<float*>(Cout)[idx] = v;
        else reinterpret_cast<u16*>(Cout)[idx] = f2b(v);
      }
    }
  }
}

// ---------------- rank-1 bias precompute: qrk0 = Q.rk[0], krq0 = K.rq[0] ----------------
__global__ __launch_bounds__(256) void biasqk(const u16* __restrict__ Qb,
    const u16* __restrict__ Kb, const u16* __restrict__ RKb,
    const u16* __restrict__ RQb, float* __restrict__ qrk0,
    float* __restrict__ krq0) {
  int o = blockIdx.x * 64 + (threadIdx.x >> 2);
  int sub = threadIdx.x & 3;
  int b = o >> 15, h = (o >> 11) & 15, i = o & 2047;
  size_t rbase = (size_t)(b * SEQ + i) * HID + h * HD + sub * 16;
  size_t tbase = (size_t)h * HD + sub * 16;
  float s1 = 0.f, s2 = 0.f;
  #pragma unroll
  for (int c = 0; c < 2; ++c) {
    short8 qv = *reinterpret_cast<const short8*>(&Qb[rbase + c * 8]);
    short8 rv = *reinterpret_cast<const short8*>(&RKb[tbase + c * 8]);
    short8 kv = *reinterpret_cast<const short8*>(&Kb[rbase + c * 8]);
    short8 uv = *reinterpret_cast<const short8*>(&RQb[tbase + c * 8]);
    #pragma unroll
    for (int j = 0; j < 8; ++j) {
      s1 += b2f((u16)qv[j]) * b2f((u16)rv[j]);
      s2 += b2f((u16)kv[j]) * b2f((u16)uv[j]);
    }
  }
  s1 += __shfl_xor(s1, 1); s1 += __shfl_xor(s1, 2);
  s2 += __shfl_xor(s2, 1); s2 += __shfl_xor(s2, 2);
  if (sub == 0) { qrk0[o] = s1; krq0[o] = s2; }
}

// ---------------- band bias precompute (validated G machinery) ----------------
// band[(bh + q)*512 + d] = Q[q].rk[511-d] + K[q-d].rq[511-d],  d in [0,511]
__global__ __launch_bounds__(256, 3) void bias_kernel(
    const u16* __restrict__ Qb, const u16* __restrict__ Kb,
    const u16* __restrict__ RKb, const u16* __restrict__ RQb,
    u16* __restrict__ band) {
  __shared__ u16 smem[20992]; // 41984 B -> 3 blocks/CU
  const int KsO = 0, UO = 4096;
  const int RKO = UO, RQO = UO + 8192;
  const int G1O = UO, G2O = UO + 8448;

  int qt = blockIdx.x;
  int h = blockIdx.y, b = blockIdx.z;
  int q0 = qt * 64;
  int t = threadIdx.x;
  int wv = t >> 6, lane = t & 63, l15 = lane & 15, lg = lane >> 4;
  int qs = q0 + wv * 16;
  int hoff = h * HD;
  int bh = (b * NH + h) * SEQ;

  size_t qgrow = (size_t)(b * SEQ + qs + l15) * HID + hoff;
  short8 aq0 = *reinterpret_cast<const short8*>(&Qb[qgrow + lg * 8]);
  short8 aq1 = *reinterpret_cast<const short8*>(&Qb[qgrow + 32 + lg * 8]);

  const f32x4 Z = (f32x4){0.f, 0.f, 0.f, 0.f};
  int vr = t >> 2, vc8 = (t & 3) * 8;
  int ktlo = qt - 8; if (ktlo < 0) ktlo = 0;

  for (int kt = ktlo; kt <= qt; ++kt) {
    int k0 = kt * 64;
    int dt = qt - kt;
    int wlo = 448 - 64 * dt; if (wlo < 0) wlo = 0;
    __syncthreads(); // #1: previous iteration's gathers done
    {
      const u16* kg = &Kb[(size_t)(b * SEQ + k0 + vr) * HID + hoff];
      int c0 = vc8 >> 3;
      *reinterpret_cast<short8*>(&smem[KsO + vr * 64 + 8 * (c0 ^ (vr & 7))]) =
          *reinterpret_cast<const short8*>(&kg[vc8]);
      *reinterpret_cast<short8*>(&smem[KsO + vr * 64 + 8 * ((c0 + 4) ^ (vr & 7))]) =
          *reinterpret_cast<const short8*>(&kg[vc8 + 32]);
    }
    for (int e2 = t; e2 < 1024; e2 += 256) {
      int rr = e2 >> 3, cch = e2 & 7;
      int wr2 = wlo + rr; if (wr2 > 511) wr2 = 511;
      size_t gb = (size_t)wr2 * HID + hoff + cch * 8;
      int slot = 8 * (cch ^ (rr & 7));
      *reinterpret_cast<short8*>(&smem[RKO + rr * 64 + slot]) =
          *reinterpret_cast<const short8*>(&RKb[gb]);
      *reinterpret_cast<short8*>(&smem[RQO + rr * 64 + slot]) =
          *reinterpret_cast<const short8*>(&RQb[gb]);
    }
    __syncthreads(); // #2: staging visible
    u32 g1p[16], g2p[16];
    #pragma unroll
    for (int cw = 0; cw < 8; ++cw) {
      short8 r0 = swz8(&smem[RKO], cw * 16 + l15, lg);
      short8 r1 = swz8(&smem[RKO], cw * 16 + l15, 4 + lg);
      f32x4 g = mfma16(r1, aq1, mfma16(r0, aq0, Z));
      g1p[2 * cw] = pk2(g[0], g[1]);
      g1p[2 * cw + 1] = pk2(g[2], g[3]);
    }
    short8 kw0 = swz8(&smem[KsO], wv * 16 + l15, lg);
    short8 kw1 = swz8(&smem[KsO], wv * 16 + l15, 4 + lg);
    #pragma unroll
    for (int cw = 0; cw < 8; ++cw) {
      short8 u0 = swz8(&smem[RQO], cw * 16 + l15, lg);
      short8 u1 = swz8(&smem[RQO], cw * 16 + l15, 4 + lg);
      f32x4 g = mfma16(u1, kw1, mfma16(u0, kw0, Z));
      g2p[2 * cw] = pk2(g[0], g[1]);
      g2p[2 * cw + 1] = pk2(g[2], g[3]);
    }
    __syncthreads(); // #3: band reads done; U reusable for G
    #pragma unroll
    for (int cw = 0; cw < 8; ++cw) {
      *reinterpret_cast<uint2*>(&smem[G1O + (wv * 16 + l15) * 132 + cw * 16 + lg * 4]) =
          make_uint2(g1p[2 * cw], g1p[2 * cw + 1]);
      *reinterpret_cast<uint2*>(&smem[G2O + (wv * 16 + l15) * 132 + cw * 16 + lg * 4]) =
          make_uint2(g2p[2 * cw], g2p[2 * cw + 1]);
    }
    __syncthreads(); // #4: G visible
    #pragma unroll
    for (int c = 0; c < 4; ++c) {
      #pragma unroll
      for (int r = 0; r < 4; ++r) {
        int q = qs + lg * 4 + r;
        int k = k0 + c * 16 + l15;
        int d = q - k;
        int wi = 511 - d - wlo; if (wi < 0) wi = 0;
        float v = b2f(smem[G1O + (wv * 16 + lg * 4 + r) * 132 + wi]) +
                  b2f(smem[G2O + (c * 16 + l15) * 132 + wi]);
        if (d >= 0 && d < 512)
          band[((size_t)(bh + q) << 9) + d] = f2b(v);
      }
    }
  }
}

// ---------------- fused DeBERTa flash attention: paired q-tiles, shared K/V stream ----------------
// Block i handles qtA = 31-i (kt=0..qtA) and qtB = i (kt=0..qtB): 33 work-units/block.
// LDS (u16): Ks0 @0, Ks1 @4096 ([64][64] XOR-swz); Vt0 @8192, Vt1 @12800
// ([64 d][72] add-rotate); Ps @17408 ([64 q][72] add-rotate, reused A then B). 44032 B.
__global__ __launch_bounds__(256, 2) void attn_mfma(
    const u16* __restrict__ Qb, const u16* __restrict__ Kb,
    const u16* __restrict__ Vb, const float* __restrict__ qrk0,
    const float* __restrict__ krq0, const u16* __restrict__ band,
    u16* __restrict__ ATT) {
  __shared__ u16 smem[22016];
  const int KsB[2] = {0, 4096};
  const int VtB[2] = {8192, 12800};
  const int PsO = 17408;

  int qtA = 31 - (int)blockIdx.x; // heavy stream
  int qtB = (int)blockIdx.x;      // light stream (prefix of A's k-range)
  int h = blockIdx.y, b = blockIdx.z;
  int t = threadIdx.x;
  int wv = t >> 6, lane = t & 63, l15 = lane & 15, lg = lane >> 4;
  int hoff = h * HD;
  int bh = (b * NH + h) * SEQ;
  const u16* bandq = band + ((size_t)bh << 9);

  int qsA = qtA * 64 + wv * 16;
  int qsB = qtB * 64 + wv * 16;
  size_t qgA = (size_t)(b * SEQ + qsA + l15) * HID + hoff;
  size_t qgB = (size_t)(b * SEQ + qsB + l15) * HID + hoff;
  short8 aqA0 = *reinterpret_cast<const short8*>(&Qb[qgA + lg * 8]);
  short8 aqA1 = *reinterpret_cast<const short8*>(&Qb[qgA + 32 + lg * 8]);
  short8 aqB0 = *reinterpret_cast<const short8*>(&Qb[qgB + lg * 8]);
  short8 aqB1 = *reinterpret_cast<const short8*>(&Qb[qgB + 32 + lg * 8]);
  float qb0A[4], qb0B[4];
  #pragma unroll
  for (int r = 0; r < 4; ++r) {
    qb0A[r] = qrk0[bh + qsA + lg * 4 + r];
    qb0B[r] = qrk0[bh + qsB + lg * 4 + r];
  }

  float mA[4], lA[4], mB[4], lB[4];
  f32x4 oA[4], oB[4];
  #pragma unroll
  for (int r = 0; r < 4; ++r) { mA[r] = -INFINITY; lA[r] = 0.f; mB[r] = -INFINITY; lB[r] = 0.f; }
  #pragma unroll
  for (int c = 0; c < 4; ++c) {
    oA[c] = (f32x4){0.f, 0.f, 0.f, 0.f};
    oB[c] = (f32x4){0.f, 0.f, 0.f, 0.f};
  }

  const f32x4 Z = (f32x4){0.f, 0.f, 0.f, 0.f};
  int vr = t >> 2, vc8 = (t & 3) * 8;
  int c0s = vc8 >> 3;
  // hoisted LDS offsets (bases alternate by +4096/+4608)
  int kslot0 = vr * 64 + 8 * (c0s ^ (vr & 7));
  int kslot1 = vr * 64 + 8 * ((c0s + 4) ^ (vr & 7));
  int vslot[16];
  #pragma unroll
  for (int j = 0; j < 8; ++j) {
    vslot[j] = vrot(vc8 + j, vr);
    vslot[8 + j] = vrot(vc8 + 32 + j, vr);
  }

  // ---- prologue: stage tile 0 into buffer 0 ----
  {
    const u16* kg = &Kb[(size_t)(b * SEQ + vr) * HID + hoff];
    short8 k0v = *reinterpret_cast<const short8*>(&kg[vc8]);
    short8 k1v = *reinterpret_cast<const short8*>(&kg[vc8 + 32]);
    *reinterpret_cast<short8*>(&smem[KsB[0] + kslot0]) = k0v;
    *reinterpret_cast<short8*>(&smem[KsB[0] + kslot1]) = k1v;
    const u16* vg = &Vb[(size_t)(b * SEQ + vr) * HID + hoff];
    short8 v0v = *reinterpret_cast<const short8*>(&vg[vc8]);
    short8 v1v = *reinterpret_cast<const short8*>(&vg[vc8 + 32]);
    #pragma unroll
    for (int j = 0; j < 8; ++j) smem[VtB[0] + vslot[j]] = (u16)v0v[j];
    #pragma unroll
    for (int j = 0; j < 8; ++j) smem[VtB[0] + vslot[8 + j]] = (u16)v1v[j];
  }
  __syncthreads();

  int cur = 0;
  for (int kt = 0; kt <= qtA; ++kt) {
    int k0 = kt * 64;
    int dtA = qtA - kt;
    bool doB = (kt <= qtB);
    int dtB = qtB - kt;
    bool bandedA = (dtA <= 8);
    bool bandedB = doB && (dtB <= 8);
    int ksb = KsB[cur], vtb = VtB[cur];
    int ksn = KsB[cur ^ 1], vtn = VtB[cur ^ 1];

    // ---- early loads: kq (shared), band rows, next-tile K/V prefetch ----
    float kq[4];
    #pragma unroll
    for (int c = 0; c < 4; ++c) kq[c] = krq0[bh + k0 + c * 16 + l15];
    u16 brawA[4][4], brawB[4][4];
    if (bandedA) {
      #pragma unroll
      for (int c = 0; c < 4; ++c) {
        #pragma unroll
        for (int r = 0; r < 4; ++r) {
          int q = qsA + lg * 4 + r;
          int d = q - (k0 + c * 16 + l15);
          int dc = d < 0 ? 0 : (d > 511 ? 511 : d);
          brawA[c][r] = bandq[((size_t)q << 9) + dc];
        }
      }
    }
    if (bandedB) {
      #pragma unroll
      for (int c = 0; c < 4; ++c) {
        #pragma unroll
        for (int r = 0; r < 4; ++r) {
          int q = qsB + lg * 4 + r;
          int d = q - (k0 + c * 16 + l15);
          int dc = d < 0 ? 0 : (d > 511 ? 511 : d);
          brawB[c][r] = bandq[((size_t)q << 9) + dc];
        }
      }
    }
    short8 nk0, nk1, nv0, nv1;
    if (kt < qtA) {
      const u16* kg = &Kb[(size_t)(b * SEQ + k0 + 64 + vr) * HID + hoff];
      nk0 = *reinterpret_cast<const short8*>(&kg[vc8]);
      nk1 = *reinterpret_cast<const short8*>(&kg[vc8 + 32]);
      const u16* vg = &Vb[(size_t)(b * SEQ + k0 + 64 + vr) * HID + hoff];
      nv0 = *reinterpret_cast<const short8*>(&vg[vc8]);
      nv1 = *reinterpret_cast<const short8*>(&vg[vc8 + 32]);
    }

    // ---- K fragments (shared by A and B) ----
    short8 kb0[4], kb1[4];
    #pragma unroll
    for (int c = 0; c < 4; ++c) {
      kb0[c] = swz8(&smem[ksb], c * 16 + l15, lg);
      kb1[c] = swz8(&smem[ksb], c * 16 + l15, 4 + lg);
    }
    // ---- stream A: c2c + bias + softmax ----
    f32x4 sA[4], sB[4];
    #pragma unroll
    for (int c = 0; c < 4; ++c)
      sA[c] = mfma16(aqA1, kb1[c], mfma16(aqA0, kb0[c], Z));
    if (doB) {
      #pragma unroll
      for (int c = 0; c < 4; ++c)
        sB[c] = mfma16(aqB1, kb1[c], mfma16(aqB0, kb0[c], Z));
    }
    #pragma unroll
    for (int c = 0; c < 4; ++c) {
      #pragma unroll
      for (int r = 0; r < 4; ++r) {
        float bbv;
        if (bandedA) {
          int q = qsA + lg * 4 + r;
          int d = q - (k0 + c * 16 + l15);
          bbv = (d >= 0 && d < 512) ? b2f(brawA[c][r]) : qb0A[r] + kq[c];
        } else {
          bbv = qb0A[r] + kq[c];
        }
        float v = (sA[c][r] + bbv) * SM_SCALE;
        if (dtA == 0) {
          int ql = wv * 16 + lg * 4 + r, kl = c * 16 + l15;
          if (ql < kl) v = -INFINITY;
        }
        sA[c][r] = v;
      }
    }
    if (doB) {
      #pragma unroll
      for (int c = 0; c < 4; ++c) {
        #pragma unroll
        for (int r = 0; r < 4; ++r) {
          float bbv;
          if (bandedB) {
            int q = qsB + lg * 4 + r;
            int d = q - (k0 + c * 16 + l15);
            bbv = (d >= 0 && d < 512) ? b2f(brawB[c][r]) : qb0B[r] + kq[c];
          } else {
            bbv = qb0B[r] + kq[c];
          }
          float v = (sB[c][r] + bbv) * SM_SCALE;
          if (dtB == 0) {
            int ql = wv * 16 + lg * 4 + r, kl = c * 16 + l15;
            if (ql < kl) v = -INFINITY;
          }
          sB[c][r] = v;
        }
      }
    }
    // ---- softmax A (and B interleaved by compiler: independent chains) ----
    float alA[4], alB[4];
    #pragma unroll
    for (int r = 0; r < 4; ++r) {
      float mx = fmaxf(fmaxf(sA[0][r], sA[1][r]), fmaxf(sA[2][r], sA[3][r]));
      mx = fmaxf(mx, __shfl_xor(mx, 1));
      mx = fmaxf(mx, __shfl_xor(mx, 2));
      mx = fmaxf(mx, __shfl_xor(mx, 4));
      mx = fmaxf(mx, __shfl_xor(mx, 8));
      float mn = fmaxf(mA[r], mx);
      alA[r] = __expf(mA[r] - mn);
      float ps = 0.f;
      #pragma unroll
      for (int c = 0; c < 4; ++c) {
        float p = __expf(sA[c][r] - mn);
        sA[c][r] = p;
        ps += p;
      }
      ps += __shfl_xor(ps, 1);
      ps += __shfl_xor(ps, 2);
      ps += __shfl_xor(ps, 4);
      ps += __shfl_xor(ps, 8);
      lA[r] = lA[r] * alA[r] + ps;
      mA[r] = mn;
    }
    if (doB) {
      #pragma unroll
      for (int r = 0; r < 4; ++r) {
        float mx = fmaxf(fmaxf(sB[0][r], sB[1][r]), fmaxf(sB[2][r], sB[3][r]));
        mx = fmaxf(mx, __shfl_xor(mx, 1));
        mx = fmaxf(mx, __shfl_xor(mx, 2));
        mx = fmaxf(mx, __shfl_xor(mx, 4));
        mx = fmaxf(mx, __shfl_xor(mx, 8));
        float mn = fmaxf(mB[r], mx);
        alB[r] = __expf(mB[r] - mn);
        float ps = 0.f;
        #pragma unroll
        for (int c = 0; c < 4; ++c) {
          float p = __expf(sB[c][r] - mn);
          sB[c][r] = p;
          ps += p;
        }
        ps += __shfl_xor(ps, 1);
        ps += __shfl_xor(ps, 2);
        ps += __shfl_xor(ps, 4);
        ps += __shfl_xor(ps, 8);
        lB[r] = lB[r] * alB[r] + ps;
        mB[r] = mn;
      }
    }
    // ---- V fragments (shared) ----
    short8 vb0[4], vb1[4];
    #pragma unroll
    for (int c = 0; c < 4; ++c) {
      int n = c * 16 + l15;
      vb0[c] = *reinterpret_cast<const short8*>(&smem[vtb + vrot(n, lg * 8)]);
      vb1[c] = *reinterpret_cast<const short8*>(&smem[vtb + vrot(n, 32 + lg * 8)]);
    }
    // ---- PV A (Ps round-trip, wave-local rows) ----
    #pragma unroll
    for (int c = 0; c < 4; ++c) {
      #pragma unroll
      for (int r = 0; r < 4; ++r) {
        smem[PsO + vrot(wv * 16 + lg * 4 + r, c * 16 + l15)] = f2b(sA[c][r]);
        oA[c][r] *= alA[r];
      }
    }
    int prow = wv * 16 + l15;
    {
      short8 ap0 = *reinterpret_cast<const short8*>(&smem[PsO + vrot(prow, lg * 8)]);
      short8 ap1 = *reinterpret_cast<const short8*>(&smem[PsO + vrot(prow, 32 + lg * 8)]);
      #pragma unroll
      for (int c = 0; c < 4; ++c)
        oA[c] = mfma16(ap1, vb1[c], mfma16(ap0, vb0[c], oA[c]));
    }
    // ---- PV B (same Ps rows reused; same-wave LDS ordering) ----
    if (doB) {
      #pragma unroll
      for (int c = 0; c < 4; ++c) {
        #pragma unroll
        for (int r = 0; r < 4; ++r) {
          smem[PsO + vrot(wv * 16 + lg * 4 + r, c * 16 + l15)] = f2b(sB[c][r]);
          oB[c][r] *= alB[r];
        }
      }
      short8 bp0 = *reinterpret_cast<const short8*>(&smem[PsO + vrot(prow, lg * 8)]);
      short8 bp1 = *reinterpret_cast<const short8*>(&smem[PsO + vrot(prow, 32 + lg * 8)]);
      #pragma unroll
      for (int c = 0; c < 4; ++c)
        oB[c] = mfma16(bp1, vb1[c], mfma16(bp0, vb0[c], oB[c]));
    }
    // ---- write prefetched tile into the other buffer ----
    if (kt < qtA) {
      *reinterpret_cast<short8*>(&smem[ksn + kslot0]) = nk0;
      *reinterpret_cast<short8*>(&smem[ksn + kslot1]) = nk1;
      #pragma unroll
      for (int j = 0; j < 8; ++j) smem[vtn + vslot[j]] = (u16)nv0[j];
      #pragma unroll
      for (int j = 0; j < 8; ++j) smem[vtn + vslot[8 + j]] = (u16)nv1[j];
    }
    __syncthreads(); // single barrier per tile
    cur ^= 1;
  }
  #pragma unroll
  for (int r = 0; r < 4; ++r) { lA[r] = 1.0f / lA[r]; lB[r] = 1.0f / lB[r]; }
  #pragma unroll
  for (int c = 0; c < 4; ++c) {
    #pragma unroll
    for (int r = 0; r < 4; ++r) {
      size_t obA = (size_t)(b * SEQ + qsA + lg * 4 + r) * HID + hoff + c * 16 + l15;
      ATT[obA] = f2b(oA[c][r] * lA[r]);
      size_t obB = (size_t)(b * SEQ + qsB + lg * 4 + r) * HID + hoff + c * 16 + l15;
      ATT[obB] = f2b(oB[c][r] * lB[r]);
    }
  }
}

extern "C" void kernel_launch(void* const* d_in, const int* in_sizes, int n_in,
                              void* d_out, int out_size, void* d_ws, size_t ws_size,
                              hipStream_t stream) {
  const float* x      = (const float*)d_in[0];
  const float* Wq     = (const float*)d_in[1];
  const float* bq     = (const float*)d_in[2];
  const float* Wk     = (const float*)d_in[3];
  const float* bk     = (const float*)d_in[4];
  const float* Wv     = (const float*)d_in[5];
  const float* bv     = (const float*)d_in[6];
  const float* Wo     = (const float*)d_in[7];
  const float* bo     = (const float*)d_in[8];
  const float* relpos = (const float*)d_in[9];
  const float* gamma  = (const float*)d_in[10];
  const float* beta   = (const float*)d_in[11];
  const float* Wrk    = (const float*)d_in[12];
  const float* brk    = (const float*)d_in[13];
  const float* Wrq    = (const float*)d_in[14];
  const float* brq    = (const float*)d_in[15];
  float* out = (float*)d_out;

  u16* wsu = (u16*)d_ws;
  size_t off = 0;
  auto alloc = [&](size_t n) { u16* p = wsu + off; off += n; return p; };
  u16* xb   = alloc(4194304);
  u16* Eb   = alloc(524288);
  u16* WtQ  = alloc(1048576);
  u16* WtK  = alloc(1048576);
  u16* WtV  = alloc(1048576);
  u16* WtO  = alloc(1048576);
  u16* WtRK = alloc(1048576);
  u16* WtRQ = alloc(1048576);
  u16* Qb2  = alloc(4194304);
  u16* Kb2  = alloc(4194304);
  u16* Vb2  = alloc(4194304);
  u16* ATTb = alloc(4194304);
  u16* RKb2 = alloc(524288);
  u16* RQb2 = alloc(524288);
  float* qrk0 = (float*)(wsu + off); off += 131072;
  float* krq0 = (float*)(wsu + off); off += 131072;
  u16* band = alloc(33554432); // [2*16*2048 rows][512 d] bf16 = 67 MB

  ln_kernel<<<512, 256, 0, stream>>>(relpos, gamma, beta, Eb);
  conv_bf16<<<2048, 256, 0, stream>>>(x, xb, 4194304);
  P6 p6;
  p6.s[0] = Wq; p6.s[1] = Wk; p6.s[2] = Wv; p6.s[3] = Wo; p6.s[4] = Wrk; p6.s[5] = Wrq;
  p6.d[0] = WtQ; p6.d[1] = WtK; p6.d[2] = WtV; p6.d[3] = WtO; p6.d[4] = WtRK; p6.d[5] = WtRQ;
  dim3 gT(32, 32, 6);
  transp_all<<<gT, 256, 0, stream>>>(p6);

  dim3 gBig(8, 32);
  gemm_bf16<false><<<gBig, 256, 0, stream>>>(xb, WtQ, bq, Qb2);
  gemm_bf16<false><<<gBig, 256, 0, stream>>>(xb, WtK, bk, Kb2);
  gemm_bf16<false><<<gBig, 256, 0, stream>>>(xb, WtV, bv, Vb2);
  dim3 gRel(8, 4);
  gemm_bf16<false><<<gRel, 256, 0, stream>>>(Eb, WtRK, brk, RKb2);
  gemm_bf16<false><<<gRel, 256, 0, stream>>>(Eb, WtRQ, brq, RQb2);

  biasqk<<<1024, 256, 0, stream>>>(Qb2, Kb2, RKb2, RQb2, qrk0, krq0);

  dim3 gB(32, NH, NB);
  bias_kernel<<<gB, 256, 0, stream>>>(Qb2, Kb2, RKb2, RQb2, band);

  dim3 gA(16, NH, NB); // paired q-tiles: 512 balanced blocks
  attn_mfma<<<gA, 256, 0, stream>>>(Qb2, Kb2, Vb2, qrk0, krq0, band, ATTb);

  gemm_bf16<true><<<gBig, 256, 0, stream>>>(ATTb, WtO, bo, out);
}

// Round 9
// 266.449 us; speedup vs baseline: 1.5539x; 1.2007x over previous
//
#include <hip/hip_runtime.h>
#include <math.h>

#define NH 16
#define HD 64
#define HID 1024
#define SEQ 2048
#define NB 2

typedef __attribute__((ext_vector_type(8))) short short8;
typedef __attribute__((ext_vector_type(4))) float f32x4;
typedef unsigned short u16;
typedef unsigned int u32;

constexpr float LN_EPS_C = 1e-5f;
constexpr float SM_SCALE = 0.07216878364870323f; // 1/sqrt(64*3)

__device__ inline u16 f2b(float f) {
  unsigned u = __builtin_bit_cast(unsigned, f);
  u = (u + 0x7FFFu + ((u >> 16) & 1u)) >> 16;
  return (u16)u;
}
__device__ inline float b2f(u16 h) {
  unsigned u = ((unsigned)h) << 16;
  return __builtin_bit_cast(float, u);
}
__device__ inline u32 pk2(float lo, float hi) {
  return (u32)f2b(lo) | ((u32)f2b(hi) << 16);
}
__device__ inline f32x4 mfma16(short8 a, short8 b, f32x4 c) {
  return __builtin_amdgcn_mfma_f32_16x16x32_bf16(a, b, c, 0, 0, 0);
}
// swizzled read of a [rows][64] bf16 tile whose writes used slot = chunk^(row&7)
__device__ inline short8 swz8(const u16* base, int row, int hc) {
  return *reinterpret_cast<const short8*>(&base[row * 64 + 8 * (hc ^ (row & 7))]);
}
// add-rotate swizzle for [64 row][72-stride] tiles, col in [0,64).
__device__ inline int vrot(int row, int col) {
  return row * 72 + ((col + 16 * ((row >> 3) & 3)) & 63);
}

// ---------------- LayerNorm over relpos_table rows -> bf16 ----------------
__global__ __launch_bounds__(256) void ln_kernel(const float* __restrict__ tbl,
    const float* __restrict__ gamma, const float* __restrict__ beta,
    u16* __restrict__ e) {
  int row = blockIdx.x;
  int t = threadIdx.x;
  const float4* rp = reinterpret_cast<const float4*>(tbl + (size_t)row * HID);
  float4 x = rp[t];
  float s = x.x + x.y + x.z + x.w;
  float ss = x.x * x.x + x.y * x.y + x.z * x.z + x.w * x.w;
  #pragma unroll
  for (int o = 1; o < 64; o <<= 1) {
    s += __shfl_xor(s, o);
    ss += __shfl_xor(ss, o);
  }
  __shared__ float sb[4], ssb[4];
  int w = t >> 6;
  if ((t & 63) == 0) { sb[w] = s; ssb[w] = ss; }
  __syncthreads();
  s = sb[0] + sb[1] + sb[2] + sb[3];
  ss = ssb[0] + ssb[1] + ssb[2] + ssb[3];
  float mu = s * (1.0f / HID);
  float var = ss * (1.0f / HID) - mu * mu;
  float rs = rsqrtf(var + LN_EPS_C);
  float4 g = reinterpret_cast<const float4*>(gamma)[t];
  float4 bt = reinterpret_cast<const float4*>(beta)[t];
  ushort4 o4;
  o4.x = f2b((x.x - mu) * rs * g.x + bt.x);
  o4.y = f2b((x.y - mu) * rs * g.y + bt.y);
  o4.z = f2b((x.z - mu) * rs * g.z + bt.z);
  o4.w = f2b((x.w - mu) * rs * g.w + bt.w);
  *reinterpret_cast<ushort4*>(&e[(size_t)row * HID + t * 4]) = o4;
}

// ---------------- f32 -> bf16 convert ----------------
__global__ __launch_bounds__(256) void conv_bf16(const float* __restrict__ src,
    u16* __restrict__ dst, int n) {
  int i = (blockIdx.x * 256 + threadIdx.x) * 8;
  if (i >= n) return;
  float4 a = *reinterpret_cast<const float4*>(&src[i]);
  float4 c = *reinterpret_cast<const float4*>(&src[i + 4]);
  short8 o;
  o[0] = (short)f2b(a.x); o[1] = (short)f2b(a.y); o[2] = (short)f2b(a.z); o[3] = (short)f2b(a.w);
  o[4] = (short)f2b(c.x); o[5] = (short)f2b(c.y); o[6] = (short)f2b(c.z); o[7] = (short)f2b(c.w);
  *reinterpret_cast<short8*>(&dst[i]) = o;
}

// ---------------- all 6 weight transposes in one launch ----------------
struct P6 {
  const float* s[6];
  u16* d[6];
};
__global__ __launch_bounds__(256) void transp_all(P6 p) {
  __shared__ float T[32][33];
  const float* W = p.s[blockIdx.z];
  u16* Wt = p.d[blockIdx.z];
  int bn = blockIdx.x * 32, bk = blockIdx.y * 32;
  int t = threadIdx.x;
  int r = t >> 3, c4 = (t & 7) * 4;
  float4 v = *reinterpret_cast<const float4*>(&W[(size_t)(bk + r) * HID + bn + c4]);
  T[r][c4 + 0] = v.x; T[r][c4 + 1] = v.y; T[r][c4 + 2] = v.z; T[r][c4 + 3] = v.w;
  __syncthreads();
  int n = t >> 3, k4 = (t & 7) * 4;
  ushort4 o;
  o.x = f2b(T[k4 + 0][n]); o.y = f2b(T[k4 + 1][n]);
  o.z = f2b(T[k4 + 2][n]); o.w = f2b(T[k4 + 3][n]);
  *reinterpret_cast<ushort4*>(&Wt[(size_t)(bn + n) * HID + bk + k4]) = o;
}

// ---------------- bf16 MFMA GEMM: 512 threads (2 waves/SIMD), 128x128, BK=64 ----------------
template <bool F32OUT>
__global__ __launch_bounds__(512) void gemm_bf16(const u16* __restrict__ A,
    const u16* __restrict__ Bt, const float* __restrict__ bias,
    void* __restrict__ Cout) {
  __shared__ u16 Al[8192]; // [128][64] swizzled
  __shared__ u16 Bl[8192];
  int t = threadIdx.x;
  int cb = blockIdx.x * 128, rb = blockIdx.y * 128;
  int wv = t >> 6, lane = t & 63, l15 = lane & 15, lg = lane >> 4;
  int wr = (wv >> 2) * 64, wc = (wv & 3) * 32;
  int srow = t >> 2, sch = t & 3;
  f32x4 acc[4][2];
  #pragma unroll
  for (int i = 0; i < 4; ++i)
    #pragma unroll
    for (int j = 0; j < 2; ++j) acc[i][j] = (f32x4){0.f, 0.f, 0.f, 0.f};
  const u16* Ap = A + (size_t)(rb + srow) * HID;
  const u16* Bp = Bt + (size_t)(cb + srow) * HID;
  int slot0 = 8 * (sch ^ (srow & 7));
  int slot1 = 8 * ((sch + 4) ^ (srow & 7));
  short8 pa0 = *reinterpret_cast<const short8*>(&Ap[sch * 8]);
  short8 pa1 = *reinterpret_cast<const short8*>(&Ap[(sch + 4) * 8]);
  short8 pb0 = *reinterpret_cast<const short8*>(&Bp[sch * 8]);
  short8 pb1 = *reinterpret_cast<const short8*>(&Bp[(sch + 4) * 8]);
  for (int kk = 0; kk < HID; kk += 64) {
    __syncthreads();
    *reinterpret_cast<short8*>(&Al[srow * 64 + slot0]) = pa0;
    *reinterpret_cast<short8*>(&Al[srow * 64 + slot1]) = pa1;
    *reinterpret_cast<short8*>(&Bl[srow * 64 + slot0]) = pb0;
    *reinterpret_cast<short8*>(&Bl[srow * 64 + slot1]) = pb1;
    __syncthreads();
    if (kk + 64 < HID) {
      pa0 = *reinterpret_cast<const short8*>(&Ap[kk + 64 + sch * 8]);
      pa1 = *reinterpret_cast<const short8*>(&Ap[kk + 64 + (sch + 4) * 8]);
      pb0 = *reinterpret_cast<const short8*>(&Bp[kk + 64 + sch * 8]);
      pb1 = *reinterpret_cast<const short8*>(&Bp[kk + 64 + (sch + 4) * 8]);
    }
    #pragma unroll
    for (int s = 0; s < 2; ++s) {
      short8 am[4], bn[2];
      #pragma unroll
      for (int i = 0; i < 4; ++i) am[i] = swz8(Al, wr + i * 16 + l15, s * 4 + lg);
      #pragma unroll
      for (int j = 0; j < 2; ++j) bn[j] = swz8(Bl, wc + j * 16 + l15, s * 4 + lg);
      #pragma unroll
      for (int i = 0; i < 4; ++i)
        #pragma unroll
        for (int j = 0; j < 2; ++j)
          acc[i][j] = mfma16(am[i], bn[j], acc[i][j]);
    }
  }
  #pragma unroll
  for (int j = 0; j < 2; ++j) {
    float bv = bias[cb + wc + j * 16 + l15];
    #pragma unroll
    for (int i = 0; i < 4; ++i) {
      #pragma unroll
      for (int r = 0; r < 4; ++r) {
        size_t idx = (size_t)(rb + wr + i * 16 + lg * 4 + r) * HID + cb + wc + j * 16 + l15;
        float v = acc[i][j][r] + bv;
        if (F32OUT) reinterpret_cast<float*>(Cout)[idx] = v;
        else reinterpret_cast<u16*>(Cout)[idx] = f2b(v);
      }
    }
  }
}

// ---------------- rank-1 bias precompute: qrk0 = Q.rk[0], krq0 = K.rq[0] ----------------
__global__ __launch_bounds__(256) void biasqk(const u16* __restrict__ Qb,
    const u16* __restrict__ Kb, const u16* __restrict__ RKb,
    const u16* __restrict__ RQb, float* __restrict__ qrk0,
    float* __restrict__ krq0) {
  int o = blockIdx.x * 64 + (threadIdx.x >> 2);
  int sub = threadIdx.x & 3;
  int b = o >> 15, h = (o >> 11) & 15, i = o & 2047;
  size_t rbase = (size_t)(b * SEQ + i) * HID + h * HD + sub * 16;
  size_t tbase = (size_t)h * HD + sub * 16;
  float s1 = 0.f, s2 = 0.f;
  #pragma unroll
  for (int c = 0; c < 2; ++c) {
    short8 qv = *reinterpret_cast<const short8*>(&Qb[rbase + c * 8]);
    short8 rv = *reinterpret_cast<const short8*>(&RKb[tbase + c * 8]);
    short8 kv = *reinterpret_cast<const short8*>(&Kb[rbase + c * 8]);
    short8 uv = *reinterpret_cast<const short8*>(&RQb[tbase + c * 8]);
    #pragma unroll
    for (int j = 0; j < 8; ++j) {
      s1 += b2f((u16)qv[j]) * b2f((u16)rv[j]);
      s2 += b2f((u16)kv[j]) * b2f((u16)uv[j]);
    }
  }
  s1 += __shfl_xor(s1, 1); s1 += __shfl_xor(s1, 2);
  s2 += __shfl_xor(s2, 1); s2 += __shfl_xor(s2, 2);
  if (sub == 0) { qrk0[o] = s1; krq0[o] = s2; }
}

// ---------------- band bias precompute -> per-tile thread-ordered layout ----------------
// Tile (b,h,qt,dt), dt<=min(qt,8): 4096 u16; thread t's 16 elems at [t*16 + c*4 + r],
// elem (c,r) = bias(q = qt*64+wv*16+lg*4+r, k = (qt-dt)*64+c*16+l15).
// d>511 correctly folds to the rank-1 value via the wi clamp; d<0 entries are garbage
// (masked by causal mask downstream, only occurs on dt==0).
__global__ __launch_bounds__(256, 3) void bias_kernel(
    const u16* __restrict__ Qb, const u16* __restrict__ Kb,
    const u16* __restrict__ RKb, const u16* __restrict__ RQb,
    u16* __restrict__ bandT) {
  __shared__ u16 smem[20992]; // 41984 B -> 3 blocks/CU
  const int KsO = 0, UO = 4096;
  const int RKO = UO, RQO = UO + 8192;
  const int G1O = UO, G2O = UO + 8448;

  int qt = blockIdx.x;
  int h = blockIdx.y, b = blockIdx.z;
  int q0 = qt * 64;
  int t = threadIdx.x;
  int wv = t >> 6, lane = t & 63, l15 = lane & 15, lg = lane >> 4;
  int qs = q0 + wv * 16;
  int hoff = h * HD;

  size_t qgrow = (size_t)(b * SEQ + qs + l15) * HID + hoff;
  short8 aq0 = *reinterpret_cast<const short8*>(&Qb[qgrow + lg * 8]);
  short8 aq1 = *reinterpret_cast<const short8*>(&Qb[qgrow + 32 + lg * 8]);

  const f32x4 Z = (f32x4){0.f, 0.f, 0.f, 0.f};
  int vr = t >> 2, vc8 = (t & 3) * 8;
  int ktlo = qt - 8; if (ktlo < 0) ktlo = 0;
  size_t tbase = (((size_t)(b * NH + h) * 32 + qt) * 9) << 12;

  for (int kt = ktlo; kt <= qt; ++kt) {
    int k0 = kt * 64;
    int dt = qt - kt;
    int wlo = 448 - 64 * dt; if (wlo < 0) wlo = 0;
    __syncthreads(); // #1: previous iteration's gathers done
    {
      const u16* kg = &Kb[(size_t)(b * SEQ + k0 + vr) * HID + hoff];
      int c0 = vc8 >> 3;
      *reinterpret_cast<short8*>(&smem[KsO + vr * 64 + 8 * (c0 ^ (vr & 7))]) =
          *reinterpret_cast<const short8*>(&kg[vc8]);
      *reinterpret_cast<short8*>(&smem[KsO + vr * 64 + 8 * ((c0 + 4) ^ (vr & 7))]) =
          *reinterpret_cast<const short8*>(&kg[vc8 + 32]);
    }
    for (int e2 = t; e2 < 1024; e2 += 256) {
      int rr = e2 >> 3, cch = e2 & 7;
      int wr2 = wlo + rr; if (wr2 > 511) wr2 = 511;
      size_t gb = (size_t)wr2 * HID + hoff + cch * 8;
      int slot = 8 * (cch ^ (rr & 7));
      *reinterpret_cast<short8*>(&smem[RKO + rr * 64 + slot]) =
          *reinterpret_cast<const short8*>(&RKb[gb]);
      *reinterpret_cast<short8*>(&smem[RQO + rr * 64 + slot]) =
          *reinterpret_cast<const short8*>(&RQb[gb]);
    }
    __syncthreads(); // #2: staging visible
    u32 g1p[16], g2p[16];
    #pragma unroll
    for (int cw = 0; cw < 8; ++cw) {
      short8 r0 = swz8(&smem[RKO], cw * 16 + l15, lg);
      short8 r1 = swz8(&smem[RKO], cw * 16 + l15, 4 + lg);
      f32x4 g = mfma16(r1, aq1, mfma16(r0, aq0, Z));
      g1p[2 * cw] = pk2(g[0], g[1]);
      g1p[2 * cw + 1] = pk2(g[2], g[3]);
    }
    short8 kw0 = swz8(&smem[KsO], wv * 16 + l15, lg);
    short8 kw1 = swz8(&smem[KsO], wv * 16 + l15, 4 + lg);
    #pragma unroll
    for (int cw = 0; cw < 8; ++cw) {
      short8 u0 = swz8(&smem[RQO], cw * 16 + l15, lg);
      short8 u1 = swz8(&smem[RQO], cw * 16 + l15, 4 + lg);
      f32x4 g = mfma16(u1, kw1, mfma16(u0, kw0, Z));
      g2p[2 * cw] = pk2(g[0], g[1]);
      g2p[2 * cw + 1] = pk2(g[2], g[3]);
    }
    __syncthreads(); // #3: band reads done; U reusable for G
    #pragma unroll
    for (int cw = 0; cw < 8; ++cw) {
      *reinterpret_cast<uint2*>(&smem[G1O + (wv * 16 + l15) * 132 + cw * 16 + lg * 4]) =
          make_uint2(g1p[2 * cw], g1p[2 * cw + 1]);
      *reinterpret_cast<uint2*>(&smem[G2O + (wv * 16 + l15) * 132 + cw * 16 + lg * 4]) =
          make_uint2(g2p[2 * cw], g2p[2 * cw + 1]);
    }
    __syncthreads(); // #4: G visible
    // ---- gather + coalesced per-tile write ----
    u16* outp = bandT + tbase + ((size_t)dt << 12) + t * 16;
    #pragma unroll
    for (int c = 0; c < 4; ++c) {
      float vv[4];
      #pragma unroll
      for (int r = 0; r < 4; ++r) {
        int q = qs + lg * 4 + r;
        int k = k0 + c * 16 + l15;
        int wi = 511 - (q - k) - wlo; if (wi < 0) wi = 0;
        vv[r] = b2f(smem[G1O + (wv * 16 + lg * 4 + r) * 132 + wi]) +
                b2f(smem[G2O + (c * 16 + l15) * 132 + wi]);
      }
      *reinterpret_cast<uint2*>(outp + c * 4) =
          make_uint2(pk2(vv[0], vv[1]), pk2(vv[2], vv[3]));
    }
  }
}

// ---------------- fused DeBERTa flash attention: paired q-tiles, tile-layout bias ----------------
// Block i: qtA = 31-i, qtB = i; shared K/V stream. LDS as round 8.
__global__ __launch_bounds__(256, 2) void attn_mfma(
    const u16* __restrict__ Qb, const u16* __restrict__ Kb,
    const u16* __restrict__ Vb, const float* __restrict__ qrk0,
    const float* __restrict__ krq0, const u16* __restrict__ bandT,
    u16* __restrict__ ATT) {
  __shared__ u16 smem[22016];
  const int KsB[2] = {0, 4096};
  const int VtB[2] = {8192, 12800};
  const int PsO = 17408;

  int qtA = 31 - (int)blockIdx.x; // heavy stream
  int qtB = (int)blockIdx.x;      // light stream (prefix of A's k-range)
  int h = blockIdx.y, b = blockIdx.z;
  int t = threadIdx.x;
  int wv = t >> 6, lane = t & 63, l15 = lane & 15, lg = lane >> 4;
  int hoff = h * HD;
  int bh = (b * NH + h) * SEQ;
  size_t tbaseA = (((size_t)(b * NH + h) * 32 + qtA) * 9) << 12;
  size_t tbaseB = (((size_t)(b * NH + h) * 32 + qtB) * 9) << 12;

  int qsA = qtA * 64 + wv * 16;
  int qsB = qtB * 64 + wv * 16;
  size_t qgA = (size_t)(b * SEQ + qsA + l15) * HID + hoff;
  size_t qgB = (size_t)(b * SEQ + qsB + l15) * HID + hoff;
  short8 aqA0 = *reinterpret_cast<const short8*>(&Qb[qgA + lg * 8]);
  short8 aqA1 = *reinterpret_cast<const short8*>(&Qb[qgA + 32 + lg * 8]);
  short8 aqB0 = *reinterpret_cast<const short8*>(&Qb[qgB + lg * 8]);
  short8 aqB1 = *reinterpret_cast<const short8*>(&Qb[qgB + 32 + lg * 8]);
  float qb0A[4], qb0B[4];
  #pragma unroll
  for (int r = 0; r < 4; ++r) {
    qb0A[r] = qrk0[bh + qsA + lg * 4 + r];
    qb0B[r] = qrk0[bh + qsB + lg * 4 + r];
  }

  float mA[4], lA[4], mB[4], lB[4];
  f32x4 oA[4], oB[4];
  #pragma unroll
  for (int r = 0; r < 4; ++r) { mA[r] = -INFINITY; lA[r] = 0.f; mB[r] = -INFINITY; lB[r] = 0.f; }
  #pragma unroll
  for (int c = 0; c < 4; ++c) {
    oA[c] = (f32x4){0.f, 0.f, 0.f, 0.f};
    oB[c] = (f32x4){0.f, 0.f, 0.f, 0.f};
  }

  const f32x4 Z = (f32x4){0.f, 0.f, 0.f, 0.f};
  int vr = t >> 2, vc8 = (t & 3) * 8;
  int c0s = vc8 >> 3;
  int kslot0 = vr * 64 + 8 * (c0s ^ (vr & 7));
  int kslot1 = vr * 64 + 8 * ((c0s + 4) ^ (vr & 7));
  int vslot[16];
  #pragma unroll
  for (int j = 0; j < 8; ++j) {
    vslot[j] = vrot(vc8 + j, vr);
    vslot[8 + j] = vrot(vc8 + 32 + j, vr);
  }

  // ---- prologue: stage tile 0 into buffer 0 ----
  {
    const u16* kg = &Kb[(size_t)(b * SEQ + vr) * HID + hoff];
    short8 k0v = *reinterpret_cast<const short8*>(&kg[vc8]);
    short8 k1v = *reinterpret_cast<const short8*>(&kg[vc8 + 32]);
    *reinterpret_cast<short8*>(&smem[KsB[0] + kslot0]) = k0v;
    *reinterpret_cast<short8*>(&smem[KsB[0] + kslot1]) = k1v;
    const u16* vg = &Vb[(size_t)(b * SEQ + vr) * HID + hoff];
    short8 v0v = *reinterpret_cast<const short8*>(&vg[vc8]);
    short8 v1v = *reinterpret_cast<const short8*>(&vg[vc8 + 32]);
    #pragma unroll
    for (int j = 0; j < 8; ++j) smem[VtB[0] + vslot[j]] = (u16)v0v[j];
    #pragma unroll
    for (int j = 0; j < 8; ++j) smem[VtB[0] + vslot[8 + j]] = (u16)v1v[j];
  }
  __syncthreads();

  int cur = 0;
  for (int kt = 0; kt <= qtA; ++kt) {
    int k0 = kt * 64;
    int dtA = qtA - kt;
    bool doB = (kt <= qtB);
    int dtB = qtB - kt;
    bool bandedA = (dtA <= 8);
    bool bandedB = doB && (dtB <= 8);
    int ksb = KsB[cur], vtb = VtB[cur];
    int ksn = KsB[cur ^ 1], vtn = VtB[cur ^ 1];

    // ---- early loads: bias tiles (coalesced), kq when needed, next K/V prefetch ----
    short8 pA0, pA1, pB0, pB1;
    if (bandedA) {
      const u16* tb = bandT + tbaseA + ((size_t)dtA << 12) + t * 16;
      pA0 = *reinterpret_cast<const short8*>(tb);
      pA1 = *reinterpret_cast<const short8*>(tb + 8);
    }
    if (bandedB) {
      const u16* tb = bandT + tbaseB + ((size_t)dtB << 12) + t * 16;
      pB0 = *reinterpret_cast<const short8*>(tb);
      pB1 = *reinterpret_cast<const short8*>(tb + 8);
    }
    float kq[4];
    if (dtA > 8 || (doB && dtB > 8)) {
      #pragma unroll
      for (int c = 0; c < 4; ++c) kq[c] = krq0[bh + k0 + c * 16 + l15];
    }
    short8 nk0, nk1, nv0, nv1;
    if (kt < qtA) {
      const u16* kg = &Kb[(size_t)(b * SEQ + k0 + 64 + vr) * HID + hoff];
      nk0 = *reinterpret_cast<const short8*>(&kg[vc8]);
      nk1 = *reinterpret_cast<const short8*>(&kg[vc8 + 32]);
      const u16* vg = &Vb[(size_t)(b * SEQ + k0 + 64 + vr) * HID + hoff];
      nv0 = *reinterpret_cast<const short8*>(&vg[vc8]);
      nv1 = *reinterpret_cast<const short8*>(&vg[vc8 + 32]);
    }

    // ---- K fragments (shared by A and B) ----
    short8 kb0[4], kb1[4];
    #pragma unroll
    for (int c = 0; c < 4; ++c) {
      kb0[c] = swz8(&smem[ksb], c * 16 + l15, lg);
      kb1[c] = swz8(&smem[ksb], c * 16 + l15, 4 + lg);
    }
    f32x4 sA[4], sB[4];
    #pragma unroll
    for (int c = 0; c < 4; ++c)
      sA[c] = mfma16(aqA1, kb1[c], mfma16(aqA0, kb0[c], Z));
    if (doB) {
      #pragma unroll
      for (int c = 0; c < 4; ++c)
        sB[c] = mfma16(aqB1, kb1[c], mfma16(aqB0, kb0[c], Z));
    }
    // ---- bias + scale + mask ----
    #pragma unroll
    for (int c = 0; c < 4; ++c) {
      #pragma unroll
      for (int r = 0; r < 4; ++r) {
        float bbv = bandedA ? b2f((u16)((c < 2 ? pA0 : pA1)[(c & 1) * 4 + r]))
                            : qb0A[r] + kq[c];
        float v = (sA[c][r] + bbv) * SM_SCALE;
        if (dtA == 0) {
          int ql = wv * 16 + lg * 4 + r, kl = c * 16 + l15;
          if (ql < kl) v = -INFINITY;
        }
        sA[c][r] = v;
      }
    }
    if (doB) {
      #pragma unroll
      for (int c = 0; c < 4; ++c) {
        #pragma unroll
        for (int r = 0; r < 4; ++r) {
          float bbv = bandedB ? b2f((u16)((c < 2 ? pB0 : pB1)[(c & 1) * 4 + r]))
                              : qb0B[r] + kq[c];
          float v = (sB[c][r] + bbv) * SM_SCALE;
          if (dtB == 0) {
            int ql = wv * 16 + lg * 4 + r, kl = c * 16 + l15;
            if (ql < kl) v = -INFINITY;
          }
          sB[c][r] = v;
        }
      }
    }
    // ---- softmax (two independent chains) ----
    float alA[4], alB[4];
    #pragma unroll
    for (int r = 0; r < 4; ++r) {
      float mx = fmaxf(fmaxf(sA[0][r], sA[1][r]), fmaxf(sA[2][r], sA[3][r]));
      mx = fmaxf(mx, __shfl_xor(mx, 1));
      mx = fmaxf(mx, __shfl_xor(mx, 2));
      mx = fmaxf(mx, __shfl_xor(mx, 4));
      mx = fmaxf(mx, __shfl_xor(mx, 8));
      float mn = fmaxf(mA[r], mx);
      alA[r] = __expf(mA[r] - mn);
      float ps = 0.f;
      #pragma unroll
      for (int c = 0; c < 4; ++c) {
        float p = __expf(sA[c][r] - mn);
        sA[c][r] = p;
        ps += p;
      }
      ps += __shfl_xor(ps, 1);
      ps += __shfl_xor(ps, 2);
      ps += __shfl_xor(ps, 4);
      ps += __shfl_xor(ps, 8);
      lA[r] = lA[r] * alA[r] + ps;
      mA[r] = mn;
    }
    if (doB) {
      #pragma unroll
      for (int r = 0; r < 4; ++r) {
        float mx = fmaxf(fmaxf(sB[0][r], sB[1][r]), fmaxf(sB[2][r], sB[3][r]));
        mx = fmaxf(mx, __shfl_xor(mx, 1));
        mx = fmaxf(mx, __shfl_xor(mx, 2));
        mx = fmaxf(mx, __shfl_xor(mx, 4));
        mx = fmaxf(mx, __shfl_xor(mx, 8));
        float mn = fmaxf(mB[r], mx);
        alB[r] = __expf(mB[r] - mn);
        float ps = 0.f;
        #pragma unroll
        for (int c = 0; c < 4; ++c) {
          float p = __expf(sB[c][r] - mn);
          sB[c][r] = p;
          ps += p;
        }
        ps += __shfl_xor(ps, 1);
        ps += __shfl_xor(ps, 2);
        ps += __shfl_xor(ps, 4);
        ps += __shfl_xor(ps, 8);
        lB[r] = lB[r] * alB[r] + ps;
        mB[r] = mn;
      }
    }
    // ---- V fragments (shared) ----
    short8 vb0[4], vb1[4];
    #pragma unroll
    for (int c = 0; c < 4; ++c) {
      int n = c * 16 + l15;
      vb0[c] = *reinterpret_cast<const short8*>(&smem[vtb + vrot(n, lg * 8)]);
      vb1[c] = *reinterpret_cast<const short8*>(&smem[vtb + vrot(n, 32 + lg * 8)]);
    }
    // ---- PV A ----
    #pragma unroll
    for (int c = 0; c < 4; ++c) {
      #pragma unroll
      for (int r = 0; r < 4; ++r) {
        smem[PsO + vrot(wv * 16 + lg * 4 + r, c * 16 + l15)] = f2b(sA[c][r]);
        oA[c][r] *= alA[r];
      }
    }
    int prow = wv * 16 + l15;
    {
      short8 ap0 = *reinterpret_cast<const short8*>(&smem[PsO + vrot(prow, lg * 8)]);
      short8 ap1 = *reinterpret_cast<const short8*>(&smem[PsO + vrot(prow, 32 + lg * 8)]);
      #pragma unroll
      for (int c = 0; c < 4; ++c)
        oA[c] = mfma16(ap1, vb1[c], mfma16(ap0, vb0[c], oA[c]));
    }
    // ---- PV B (same Ps rows reused; same-wave ordering) ----
    if (doB) {
      #pragma unroll
      for (int c = 0; c < 4; ++c) {
        #pragma unroll
        for (int r = 0; r < 4; ++r) {
          smem[PsO + vrot(wv * 16 + lg * 4 + r, c * 16 + l15)] = f2b(sB[c][r]);
          oB[c][r] *= alB[r];
        }
      }
      short8 bp0 = *reinterpret_cast<const short8*>(&smem[PsO + vrot(prow, lg * 8)]);
      short8 bp1 = *reinterpret_cast<const short8*>(&smem[PsO + vrot(prow, 32 + lg * 8)]);
      #pragma unroll
      for (int c = 0; c < 4; ++c)
        oB[c] = mfma16(bp1, vb1[c], mfma16(bp0, vb0[c], oB[c]));
    }
    // ---- write prefetched tile into the other buffer ----
    if (kt < qtA) {
      *reinterpret_cast<short8*>(&smem[ksn + kslot0]) = nk0;
      *reinterpret_cast<short8*>(&smem[ksn + kslot1]) = nk1;
      #pragma unroll
      for (int j = 0; j < 8; ++j) smem[vtn + vslot[j]] = (u16)nv0[j];
      #pragma unroll
      for (int j = 0; j < 8; ++j) smem[vtn + vslot[8 + j]] = (u16)nv1[j];
    }
    __syncthreads(); // single barrier per tile
    cur ^= 1;
  }
  #pragma unroll
  for (int r = 0; r < 4; ++r) { lA[r] = 1.0f / lA[r]; lB[r] = 1.0f / lB[r]; }
  #pragma unroll
  for (int c = 0; c < 4; ++c) {
    #pragma unroll
    for (int r = 0; r < 4; ++r) {
      size_t obA = (size_t)(b * SEQ + qsA + lg * 4 + r) * HID + hoff + c * 16 + l15;
      ATT[obA] = f2b(oA[c][r] * lA[r]);
      size_t obB = (size_t)(b * SEQ + qsB + lg * 4 + r) * HID + hoff + c * 16 + l15;
      ATT[obB] = f2b(oB[c][r] * lB[r]);
    }
  }
}

extern "C" void kernel_launch(void* const* d_in, const int* in_sizes, int n_in,
                              void* d_out, int out_size, void* d_ws, size_t ws_size,
                              hipStream_t stream) {
  const float* x      = (const float*)d_in[0];
  const float* Wq     = (const float*)d_in[1];
  const float* bq     = (const float*)d_in[2];
  const float* Wk     = (const float*)d_in[3];
  const float* bk     = (const float*)d_in[4];
  const float* Wv     = (const float*)d_in[5];
  const float* bv     = (const float*)d_in[6];
  const float* Wo     = (const float*)d_in[7];
  const float* bo     = (const float*)d_in[8];
  const float* relpos = (const float*)d_in[9];
  const float* gamma  = (const float*)d_in[10];
  const float* beta   = (const float*)d_in[11];
  const float* Wrk    = (const float*)d_in[12];
  const float* brk    = (const float*)d_in[13];
  const float* Wrq    = (const float*)d_in[14];
  const float* brq    = (const float*)d_in[15];
  float* out = (float*)d_out;

  u16* wsu = (u16*)d_ws;
  size_t off = 0;
  auto alloc = [&](size_t n) { u16* p = wsu + off; off += n; return p; };
  u16* xb   = alloc(4194304);
  u16* Eb   = alloc(524288);
  u16* WtQ  = alloc(1048576);
  u16* WtK  = alloc(1048576);
  u16* WtV  = alloc(1048576);
  u16* WtO  = alloc(1048576);
  u16* WtRK = alloc(1048576);
  u16* WtRQ = alloc(1048576);
  u16* Qb2  = alloc(4194304);
  u16* Kb2  = alloc(4194304);
  u16* Vb2  = alloc(4194304);
  u16* ATTb = alloc(4194304);
  u16* RKb2 = alloc(524288);
  u16* RQb2 = alloc(524288);
  float* qrk0 = (float*)(wsu + off); off += 131072;
  float* krq0 = (float*)(wsu + off); off += 131072;
  u16* bandT = alloc((size_t)NB * NH * 32 * 9 * 4096); // 75.5 MB tile-layout bias

  ln_kernel<<<512, 256, 0, stream>>>(relpos, gamma, beta, Eb);
  conv_bf16<<<2048, 256, 0, stream>>>(x, xb, 4194304);
  P6 p6;
  p6.s[0] = Wq; p6.s[1] = Wk; p6.s[2] = Wv; p6.s[3] = Wo; p6.s[4] = Wrk; p6.s[5] = Wrq;
  p6.d[0] = WtQ; p6.d[1] = WtK; p6.d[2] = WtV; p6.d[3] = WtO; p6.d[4] = WtRK; p6.d[5] = WtRQ;
  dim3 gT(32, 32, 6);
  transp_all<<<gT, 256, 0, stream>>>(p6);

  dim3 gBig(8, 32);
  gemm_bf16<false><<<gBig, 512, 0, stream>>>(xb, WtQ, bq, Qb2);
  gemm_bf16<false><<<gBig, 512, 0, stream>>>(xb, WtK, bk, Kb2);
  gemm_bf16<false><<<gBig, 512, 0, stream>>>(xb, WtV, bv, Vb2);
  dim3 gRel(8, 4);
  gemm_bf16<false><<<gRel, 512, 0, stream>>>(Eb, WtRK, brk, RKb2);
  gemm_bf16<false><<<gRel, 512, 0, stream>>>(Eb, WtRQ, brq, RQb2);

  biasqk<<<1024, 256, 0, stream>>>(Qb2, Kb2, RKb2, RQb2, qrk0, krq0);

  dim3 gB(32, NH, NB);
  bias_kernel<<<gB, 256, 0, stream>>>(Qb2, Kb2, RKb2, RQb2, bandT);

  dim3 gA(16, NH, NB); // paired q-tiles: 512 balanced blocks
  attn_mfma<<<gA, 256, 0, stream>>>(Qb2, Kb2, Vb2, qrk0, krq0, bandT, ATTb);

  gemm_bf16<true><<<gBig, 512, 0, stream>>>(ATTb, WtO, bo, out);
}

// Round 10
// 218.890 us; speedup vs baseline: 1.8915x; 1.2173x over previous
//
#include <hip/hip_runtime.h>
#include <math.h>

#define NH 16
#define HD 64
#define HID 1024
#define SEQ 2048
#define NB 2

typedef __attribute__((ext_vector_type(8))) short short8;
typedef __attribute__((ext_vector_type(4))) float f32x4;
typedef unsigned short u16;
typedef unsigned int u32;

constexpr float LN_EPS_C = 1e-5f;
constexpr float SM_SCALE = 0.07216878364870323f; // 1/sqrt(64*3)

__device__ inline u16 f2b(float f) {
  unsigned u = __builtin_bit_cast(unsigned, f);
  u = (u + 0x7FFFu + ((u >> 16) & 1u)) >> 16;
  return (u16)u;
}
__device__ inline float b2f(u16 h) {
  unsigned u = ((unsigned)h) << 16;
  return __builtin_bit_cast(float, u);
}
__device__ inline u32 pk2(float lo, float hi) {
  return (u32)f2b(lo) | ((u32)f2b(hi) << 16);
}
__device__ inline f32x4 mfma16(short8 a, short8 b, f32x4 c) {
  return __builtin_amdgcn_mfma_f32_16x16x32_bf16(a, b, c, 0, 0, 0);
}
// swizzled read of a [rows][64] bf16 tile whose writes used slot = chunk^(row&7)
__device__ inline short8 swz8(const u16* base, int row, int hc) {
  return *reinterpret_cast<const short8*>(&base[row * 64 + 8 * (hc ^ (row & 7))]);
}
// add-rotate swizzle for [64 row][72-stride] tiles, col in [0,64).
__device__ inline int vrot(int row, int col) {
  return row * 72 + ((col + 16 * ((row >> 3) & 3)) & 63);
}
// DPP row-rotate reduction within the 16-lane row group (replaces ds_bpermute shuffles)
template <int N>
__device__ inline float rorf(float x) {
  return __builtin_bit_cast(float,
      __builtin_amdgcn_update_dpp(0, __builtin_bit_cast(int, x),
                                  0x120 + N, 0xF, 0xF, true));
}
__device__ inline float rmax16(float x) {
  x = fmaxf(x, rorf<1>(x)); x = fmaxf(x, rorf<2>(x));
  x = fmaxf(x, rorf<4>(x)); x = fmaxf(x, rorf<8>(x));
  return x;
}
__device__ inline float rsum16(float x) {
  x += rorf<1>(x); x += rorf<2>(x); x += rorf<4>(x); x += rorf<8>(x);
  return x;
}

// ---------------- LayerNorm over relpos_table rows -> bf16 ----------------
__global__ __launch_bounds__(256) void ln_kernel(const float* __restrict__ tbl,
    const float* __restrict__ gamma, const float* __restrict__ beta,
    u16* __restrict__ e) {
  int row = blockIdx.x;
  int t = threadIdx.x;
  const float4* rp = reinterpret_cast<const float4*>(tbl + (size_t)row * HID);
  float4 x = rp[t];
  float s = x.x + x.y + x.z + x.w;
  float ss = x.x * x.x + x.y * x.y + x.z * x.z + x.w * x.w;
  #pragma unroll
  for (int o = 1; o < 64; o <<= 1) {
    s += __shfl_xor(s, o);
    ss += __shfl_xor(ss, o);
  }
  __shared__ float sb[4], ssb[4];
  int w = t >> 6;
  if ((t & 63) == 0) { sb[w] = s; ssb[w] = ss; }
  __syncthreads();
  s = sb[0] + sb[1] + sb[2] + sb[3];
  ss = ssb[0] + ssb[1] + ssb[2] + ssb[3];
  float mu = s * (1.0f / HID);
  float var = ss * (1.0f / HID) - mu * mu;
  float rs = rsqrtf(var + LN_EPS_C);
  float4 g = reinterpret_cast<const float4*>(gamma)[t];
  float4 bt = reinterpret_cast<const float4*>(beta)[t];
  ushort4 o4;
  o4.x = f2b((x.x - mu) * rs * g.x + bt.x);
  o4.y = f2b((x.y - mu) * rs * g.y + bt.y);
  o4.z = f2b((x.z - mu) * rs * g.z + bt.z);
  o4.w = f2b((x.w - mu) * rs * g.w + bt.w);
  *reinterpret_cast<ushort4*>(&e[(size_t)row * HID + t * 4]) = o4;
}

// ---------------- f32 -> bf16 convert ----------------
__global__ __launch_bounds__(256) void conv_bf16(const float* __restrict__ src,
    u16* __restrict__ dst, int n) {
  int i = (blockIdx.x * 256 + threadIdx.x) * 8;
  if (i >= n) return;
  float4 a = *reinterpret_cast<const float4*>(&src[i]);
  float4 c = *reinterpret_cast<const float4*>(&src[i + 4]);
  short8 o;
  o[0] = (short)f2b(a.x); o[1] = (short)f2b(a.y); o[2] = (short)f2b(a.z); o[3] = (short)f2b(a.w);
  o[4] = (short)f2b(c.x); o[5] = (short)f2b(c.y); o[6] = (short)f2b(c.z); o[7] = (short)f2b(c.w);
  *reinterpret_cast<short8*>(&dst[i]) = o;
}

// ---------------- all 6 weight transposes in one launch ----------------
struct P6 {
  const float* s[6];
  u16* d[6];
};
__global__ __launch_bounds__(256) void transp_all(P6 p) {
  __shared__ float T[32][33];
  const float* W = p.s[blockIdx.z];
  u16* Wt = p.d[blockIdx.z];
  int bn = blockIdx.x * 32, bk = blockIdx.y * 32;
  int t = threadIdx.x;
  int r = t >> 3, c4 = (t & 7) * 4;
  float4 v = *reinterpret_cast<const float4*>(&W[(size_t)(bk + r) * HID + bn + c4]);
  T[r][c4 + 0] = v.x; T[r][c4 + 1] = v.y; T[r][c4 + 2] = v.z; T[r][c4 + 3] = v.w;
  __syncthreads();
  int n = t >> 3, k4 = (t & 7) * 4;
  ushort4 o;
  o.x = f2b(T[k4 + 0][n]); o.y = f2b(T[k4 + 1][n]);
  o.z = f2b(T[k4 + 2][n]); o.w = f2b(T[k4 + 3][n]);
  *reinterpret_cast<ushort4*>(&Wt[(size_t)(bn + n) * HID + bk + k4]) = o;
}

// ---------------- bf16 MFMA GEMM: 512 threads, 128x128, BK=64, multi-output ----------------
// Bt holds concatenated weight blocks ([n_total][1024]); block's output/bias chosen by cb>>10.
struct GO {
  const float* bias[3];
  void* out[3];
};
template <bool F32OUT>
__global__ __launch_bounds__(512) void gemm_bf16(const u16* __restrict__ A,
    const u16* __restrict__ Bt, GO go) {
  __shared__ u16 Al[8192]; // [128][64] swizzled
  __shared__ u16 Bl[8192];
  int t = threadIdx.x;
  int cb = blockIdx.x * 128, rb = blockIdx.y * 128;
  int which = cb >> 10, cbl = cb & 1023;
  const float* bias = go.bias[which];
  void* Cout = go.out[which];
  int wv = t >> 6, lane = t & 63, l15 = lane & 15, lg = lane >> 4;
  int wr = (wv >> 2) * 64, wc = (wv & 3) * 32;
  int srow = t >> 2, sch = t & 3;
  f32x4 acc[4][2];
  #pragma unroll
  for (int i = 0; i < 4; ++i)
    #pragma unroll
    for (int j = 0; j < 2; ++j) acc[i][j] = (f32x4){0.f, 0.f, 0.f, 0.f};
  const u16* Ap = A + (size_t)(rb + srow) * HID;
  const u16* Bp = Bt + (size_t)(cb + srow) * HID;
  int slot0 = 8 * (sch ^ (srow & 7));
  int slot1 = 8 * ((sch + 4) ^ (srow & 7));
  short8 pa0 = *reinterpret_cast<const short8*>(&Ap[sch * 8]);
  short8 pa1 = *reinterpret_cast<const short8*>(&Ap[(sch + 4) * 8]);
  short8 pb0 = *reinterpret_cast<const short8*>(&Bp[sch * 8]);
  short8 pb1 = *reinterpret_cast<const short8*>(&Bp[(sch + 4) * 8]);
  for (int kk = 0; kk < HID; kk += 64) {
    __syncthreads();
    *reinterpret_cast<short8*>(&Al[srow * 64 + slot0]) = pa0;
    *reinterpret_cast<short8*>(&Al[srow * 64 + slot1]) = pa1;
    *reinterpret_cast<short8*>(&Bl[srow * 64 + slot0]) = pb0;
    *reinterpret_cast<short8*>(&Bl[srow * 64 + slot1]) = pb1;
    __syncthreads();
    if (kk + 64 < HID) {
      pa0 = *reinterpret_cast<const short8*>(&Ap[kk + 64 + sch * 8]);
      pa1 = *reinterpret_cast<const short8*>(&Ap[kk + 64 + (sch + 4) * 8]);
      pb0 = *reinterpret_cast<const short8*>(&Bp[kk + 64 + sch * 8]);
      pb1 = *reinterpret_cast<const short8*>(&Bp[kk + 64 + (sch + 4) * 8]);
    }
    #pragma unroll
    for (int s = 0; s < 2; ++s) {
      short8 am[4], bn[2];
      #pragma unroll
      for (int i = 0; i < 4; ++i) am[i] = swz8(Al, wr + i * 16 + l15, s * 4 + lg);
      #pragma unroll
      for (int j = 0; j < 2; ++j) bn[j] = swz8(Bl, wc + j * 16 + l15, s * 4 + lg);
      #pragma unroll
      for (int i = 0; i < 4; ++i)
        #pragma unroll
        for (int j = 0; j < 2; ++j)
          acc[i][j] = mfma16(am[i], bn[j], acc[i][j]);
    }
  }
  #pragma unroll
  for (int j = 0; j < 2; ++j) {
    float bv = bias[cbl + wc + j * 16 + l15];
    #pragma unroll
    for (int i = 0; i < 4; ++i) {
      #pragma unroll
      for (int r = 0; r < 4; ++r) {
        size_t idx = (size_t)(rb + wr + i * 16 + lg * 4 + r) * HID + cbl + wc + j * 16 + l15;
        float v = acc[i][j][r] + bv;
        if (F32OUT) reinterpret_cast<float*>(Cout)[idx] = v;
        else reinterpret_cast<u16*>(Cout)[idx] = f2b(v);
      }
    }
  }
}

// ---------------- rank-1 bias precompute (PRESCALED): qrk0 = Q.rk[0]*S, krq0 = K.rq[0]*S ----------------
__global__ __launch_bounds__(256) void biasqk(const u16* __restrict__ Qb,
    const u16* __restrict__ Kb, const u16* __restrict__ RKb,
    const u16* __restrict__ RQb, float* __restrict__ qrk0,
    float* __restrict__ krq0) {
  int o = blockIdx.x * 64 + (threadIdx.x >> 2);
  int sub = threadIdx.x & 3;
  int b = o >> 15, h = (o >> 11) & 15, i = o & 2047;
  size_t rbase = (size_t)(b * SEQ + i) * HID + h * HD + sub * 16;
  size_t tbase = (size_t)h * HD + sub * 16;
  float s1 = 0.f, s2 = 0.f;
  #pragma unroll
  for (int c = 0; c < 2; ++c) {
    short8 qv = *reinterpret_cast<const short8*>(&Qb[rbase + c * 8]);
    short8 rv = *reinterpret_cast<const short8*>(&RKb[tbase + c * 8]);
    short8 kv = *reinterpret_cast<const short8*>(&Kb[rbase + c * 8]);
    short8 uv = *reinterpret_cast<const short8*>(&RQb[tbase + c * 8]);
    #pragma unroll
    for (int j = 0; j < 8; ++j) {
      s1 += b2f((u16)qv[j]) * b2f((u16)rv[j]);
      s2 += b2f((u16)kv[j]) * b2f((u16)uv[j]);
    }
  }
  s1 += __shfl_xor(s1, 1); s1 += __shfl_xor(s1, 2);
  s2 += __shfl_xor(s2, 1); s2 += __shfl_xor(s2, 2);
  if (sub == 0) { qrk0[o] = s1 * SM_SCALE; krq0[o] = s2 * SM_SCALE; }
}

// ---------------- band bias precompute -> per-tile thread-ordered layout (PRESCALED) ----------------
__global__ __launch_bounds__(256, 3) void bias_kernel(
    const u16* __restrict__ Qb, const u16* __restrict__ Kb,
    const u16* __restrict__ RKb, const u16* __restrict__ RQb,
    u16* __restrict__ bandT) {
  __shared__ u16 smem[20992]; // 41984 B -> 3 blocks/CU
  const int KsO = 0, UO = 4096;
  const int RKO = UO, RQO = UO + 8192;
  const int G1O = UO, G2O = UO + 8448;

  int qt = blockIdx.x;
  int h = blockIdx.y, b = blockIdx.z;
  int q0 = qt * 64;
  int t = threadIdx.x;
  int wv = t >> 6, lane = t & 63, l15 = lane & 15, lg = lane >> 4;
  int qs = q0 + wv * 16;
  int hoff = h * HD;

  size_t qgrow = (size_t)(b * SEQ + qs + l15) * HID + hoff;
  short8 aq0 = *reinterpret_cast<const short8*>(&Qb[qgrow + lg * 8]);
  short8 aq1 = *reinterpret_cast<const short8*>(&Qb[qgrow + 32 + lg * 8]);

  const f32x4 Z = (f32x4){0.f, 0.f, 0.f, 0.f};
  int vr = t >> 2, vc8 = (t & 3) * 8;
  int ktlo = qt - 8; if (ktlo < 0) ktlo = 0;
  size_t tbase = (((size_t)(b * NH + h) * 32 + qt) * 9) << 12;

  for (int kt = ktlo; kt <= qt; ++kt) {
    int k0 = kt * 64;
    int dt = qt - kt;
    int wlo = 448 - 64 * dt; if (wlo < 0) wlo = 0;
    __syncthreads(); // #1: previous iteration's gathers done
    {
      const u16* kg = &Kb[(size_t)(b * SEQ + k0 + vr) * HID + hoff];
      int c0 = vc8 >> 3;
      *reinterpret_cast<short8*>(&smem[KsO + vr * 64 + 8 * (c0 ^ (vr & 7))]) =
          *reinterpret_cast<const short8*>(&kg[vc8]);
      *reinterpret_cast<short8*>(&smem[KsO + vr * 64 + 8 * ((c0 + 4) ^ (vr & 7))]) =
          *reinterpret_cast<const short8*>(&kg[vc8 + 32]);
    }
    for (int e2 = t; e2 < 1024; e2 += 256) {
      int rr = e2 >> 3, cch = e2 & 7;
      int wr2 = wlo + rr; if (wr2 > 511) wr2 = 511;
      size_t gb = (size_t)wr2 * HID + hoff + cch * 8;
      int slot = 8 * (cch ^ (rr & 7));
      *reinterpret_cast<short8*>(&smem[RKO + rr * 64 + slot]) =
          *reinterpret_cast<const short8*>(&RKb[gb]);
      *reinterpret_cast<short8*>(&smem[RQO + rr * 64 + slot]) =
          *reinterpret_cast<const short8*>(&RQb[gb]);
    }
    __syncthreads(); // #2: staging visible
    u32 g1p[16], g2p[16];
    #pragma unroll
    for (int cw = 0; cw < 8; ++cw) {
      short8 r0 = swz8(&smem[RKO], cw * 16 + l15, lg);
      short8 r1 = swz8(&smem[RKO], cw * 16 + l15, 4 + lg);
      f32x4 g = mfma16(r1, aq1, mfma16(r0, aq0, Z));
      g1p[2 * cw] = pk2(g[0], g[1]);
      g1p[2 * cw + 1] = pk2(g[2], g[3]);
    }
    short8 kw0 = swz8(&smem[KsO], wv * 16 + l15, lg);
    short8 kw1 = swz8(&smem[KsO], wv * 16 + l15, 4 + lg);
    #pragma unroll
    for (int cw = 0; cw < 8; ++cw) {
      short8 u0 = swz8(&smem[RQO], cw * 16 + l15, lg);
      short8 u1 = swz8(&smem[RQO], cw * 16 + l15, 4 + lg);
      f32x4 g = mfma16(u1, kw1, mfma16(u0, kw0, Z));
      g2p[2 * cw] = pk2(g[0], g[1]);
      g2p[2 * cw + 1] = pk2(g[2], g[3]);
    }
    __syncthreads(); // #3: band reads done; U reusable for G
    #pragma unroll
    for (int cw = 0; cw < 8; ++cw) {
      *reinterpret_cast<uint2*>(&smem[G1O + (wv * 16 + l15) * 132 + cw * 16 + lg * 4]) =
          make_uint2(g1p[2 * cw], g1p[2 * cw + 1]);
      *reinterpret_cast<uint2*>(&smem[G2O + (wv * 16 + l15) * 132 + cw * 16 + lg * 4]) =
          make_uint2(g2p[2 * cw], g2p[2 * cw + 1]);
    }
    __syncthreads(); // #4: G visible
    // ---- gather + prescale + coalesced per-tile write ----
    u16* outp = bandT + tbase + ((size_t)dt << 12) + t * 16;
    #pragma unroll
    for (int c = 0; c < 4; ++c) {
      float vv[4];
      #pragma unroll
      for (int r = 0; r < 4; ++r) {
        int q = qs + lg * 4 + r;
        int k = k0 + c * 16 + l15;
        int wi = 511 - (q - k) - wlo; if (wi < 0) wi = 0;
        vv[r] = (b2f(smem[G1O + (wv * 16 + lg * 4 + r) * 132 + wi]) +
                 b2f(smem[G2O + (c * 16 + l15) * 132 + wi])) * SM_SCALE;
      }
      *reinterpret_cast<uint2*>(outp + c * 4) =
          make_uint2(pk2(vv[0], vv[1]), pk2(vv[2], vv[3]));
    }
  }
}

// ---------------- fused DeBERTa flash attention: paired q-tiles, DPP softmax ----------------
__global__ __launch_bounds__(256, 2) void attn_mfma(
    const u16* __restrict__ Qb, const u16* __restrict__ Kb,
    const u16* __restrict__ Vb, const float* __restrict__ qrk0,
    const float* __restrict__ krq0, const u16* __restrict__ bandT,
    u16* __restrict__ ATT) {
  __shared__ u16 smem[22016];
  const int KsB[2] = {0, 4096};
  const int VtB[2] = {8192, 12800};
  const int PsO = 17408;

  int qtA = 31 - (int)blockIdx.x; // heavy stream
  int qtB = (int)blockIdx.x;      // light stream (prefix of A's k-range)
  int h = blockIdx.y, b = blockIdx.z;
  int t = threadIdx.x;
  int wv = t >> 6, lane = t & 63, l15 = lane & 15, lg = lane >> 4;
  int hoff = h * HD;
  int bh = (b * NH + h) * SEQ;
  size_t tbaseA = (((size_t)(b * NH + h) * 32 + qtA) * 9) << 12;
  size_t tbaseB = (((size_t)(b * NH + h) * 32 + qtB) * 9) << 12;

  int qsA = qtA * 64 + wv * 16;
  int qsB = qtB * 64 + wv * 16;
  size_t qgA = (size_t)(b * SEQ + qsA + l15) * HID + hoff;
  size_t qgB = (size_t)(b * SEQ + qsB + l15) * HID + hoff;
  short8 aqA0 = *reinterpret_cast<const short8*>(&Qb[qgA + lg * 8]);
  short8 aqA1 = *reinterpret_cast<const short8*>(&Qb[qgA + 32 + lg * 8]);
  short8 aqB0 = *reinterpret_cast<const short8*>(&Qb[qgB + lg * 8]);
  short8 aqB1 = *reinterpret_cast<const short8*>(&Qb[qgB + 32 + lg * 8]);
  float qb0A[4], qb0B[4];
  #pragma unroll
  for (int r = 0; r < 4; ++r) {
    qb0A[r] = qrk0[bh + qsA + lg * 4 + r];
    qb0B[r] = qrk0[bh + qsB + lg * 4 + r];
  }

  float mA[4], lA[4], mB[4], lB[4];
  f32x4 oA[4], oB[4];
  #pragma unroll
  for (int r = 0; r < 4; ++r) { mA[r] = -INFINITY; lA[r] = 0.f; mB[r] = -INFINITY; lB[r] = 0.f; }
  #pragma unroll
  for (int c = 0; c < 4; ++c) {
    oA[c] = (f32x4){0.f, 0.f, 0.f, 0.f};
    oB[c] = (f32x4){0.f, 0.f, 0.f, 0.f};
  }

  const f32x4 Z = (f32x4){0.f, 0.f, 0.f, 0.f};
  int vr = t >> 2, vc8 = (t & 3) * 8;
  int c0s = vc8 >> 3;
  int kslot0 = vr * 64 + 8 * (c0s ^ (vr & 7));
  int kslot1 = vr * 64 + 8 * ((c0s + 4) ^ (vr & 7));
  int vslot[16];
  #pragma unroll
  for (int j = 0; j < 8; ++j) {
    vslot[j] = vrot(vc8 + j, vr);
    vslot[8 + j] = vrot(vc8 + 32 + j, vr);
  }

  // ---- prologue: stage tile 0 into buffer 0 ----
  {
    const u16* kg = &Kb[(size_t)(b * SEQ + vr) * HID + hoff];
    short8 k0v = *reinterpret_cast<const short8*>(&kg[vc8]);
    short8 k1v = *reinterpret_cast<const short8*>(&kg[vc8 + 32]);
    *reinterpret_cast<short8*>(&smem[KsB[0] + kslot0]) = k0v;
    *reinterpret_cast<short8*>(&smem[KsB[0] + kslot1]) = k1v;
    const u16* vg = &Vb[(size_t)(b * SEQ + vr) * HID + hoff];
    short8 v0v = *reinterpret_cast<const short8*>(&vg[vc8]);
    short8 v1v = *reinterpret_cast<const short8*>(&vg[vc8 + 32]);
    #pragma unroll
    for (int j = 0; j < 8; ++j) smem[VtB[0] + vslot[j]] = (u16)v0v[j];
    #pragma unroll
    for (int j = 0; j < 8; ++j) smem[VtB[0] + vslot[8 + j]] = (u16)v1v[j];
  }
  __syncthreads();

  int cur = 0;
  for (int kt = 0; kt <= qtA; ++kt) {
    int k0 = kt * 64;
    int dtA = qtA - kt;
    bool doB = (kt <= qtB);
    int dtB = qtB - kt;
    bool bandedA = (dtA <= 8);
    bool bandedB = doB && (dtB <= 8);
    int ksb = KsB[cur], vtb = VtB[cur];
    int ksn = KsB[cur ^ 1], vtn = VtB[cur ^ 1];

    // ---- early loads: bias tiles (coalesced), kq when needed, next K/V prefetch ----
    short8 pA0, pA1, pB0, pB1;
    if (bandedA) {
      const u16* tb = bandT + tbaseA + ((size_t)dtA << 12) + t * 16;
      pA0 = *reinterpret_cast<const short8*>(tb);
      pA1 = *reinterpret_cast<const short8*>(tb + 8);
    }
    if (bandedB) {
      const u16* tb = bandT + tbaseB + ((size_t)dtB << 12) + t * 16;
      pB0 = *reinterpret_cast<const short8*>(tb);
      pB1 = *reinterpret_cast<const short8*>(tb + 8);
    }
    float kq[4];
    if (dtA > 8 || (doB && dtB > 8)) {
      #pragma unroll
      for (int c = 0; c < 4; ++c) kq[c] = krq0[bh + k0 + c * 16 + l15];
    }
    short8 nk0, nk1, nv0, nv1;
    if (kt < qtA) {
      const u16* kg = &Kb[(size_t)(b * SEQ + k0 + 64 + vr) * HID + hoff];
      nk0 = *reinterpret_cast<const short8*>(&kg[vc8]);
      nk1 = *reinterpret_cast<const short8*>(&kg[vc8 + 32]);
      const u16* vg = &Vb[(size_t)(b * SEQ + k0 + 64 + vr) * HID + hoff];
      nv0 = *reinterpret_cast<const short8*>(&vg[vc8]);
      nv1 = *reinterpret_cast<const short8*>(&vg[vc8 + 32]);
    }

    // ---- K fragments (shared by A and B) ----
    short8 kb0[4], kb1[4];
    #pragma unroll
    for (int c = 0; c < 4; ++c) {
      kb0[c] = swz8(&smem[ksb], c * 16 + l15, lg);
      kb1[c] = swz8(&smem[ksb], c * 16 + l15, 4 + lg);
    }
    f32x4 sA[4], sB[4];
    #pragma unroll
    for (int c = 0; c < 4; ++c)
      sA[c] = mfma16(aqA1, kb1[c], mfma16(aqA0, kb0[c], Z));
    if (doB) {
      #pragma unroll
      for (int c = 0; c < 4; ++c)
        sB[c] = mfma16(aqB1, kb1[c], mfma16(aqB0, kb0[c], Z));
    }
    // ---- bias (prescaled) + fma-scale + mask ----
    #pragma unroll
    for (int c = 0; c < 4; ++c) {
      #pragma unroll
      for (int r = 0; r < 4; ++r) {
        float bbv = bandedA ? b2f((u16)((c < 2 ? pA0 : pA1)[(c & 1) * 4 + r]))
                            : qb0A[r] + kq[c];
        float v = fmaf(sA[c][r], SM_SCALE, bbv);
        if (dtA == 0) {
          int ql = wv * 16 + lg * 4 + r, kl = c * 16 + l15;
          if (ql < kl) v = -INFINITY;
        }
        sA[c][r] = v;
      }
    }
    if (doB) {
      #pragma unroll
      for (int c = 0; c < 4; ++c) {
        #pragma unroll
        for (int r = 0; r < 4; ++r) {
          float bbv = bandedB ? b2f((u16)((c < 2 ? pB0 : pB1)[(c & 1) * 4 + r]))
                              : qb0B[r] + kq[c];
          float v = fmaf(sB[c][r], SM_SCALE, bbv);
          if (dtB == 0) {
            int ql = wv * 16 + lg * 4 + r, kl = c * 16 + l15;
            if (ql < kl) v = -INFINITY;
          }
          sB[c][r] = v;
        }
      }
    }
    // ---- softmax (DPP row reductions; two independent chains) ----
    float alA[4], alB[4];
    #pragma unroll
    for (int r = 0; r < 4; ++r) {
      float mx = fmaxf(fmaxf(sA[0][r], sA[1][r]), fmaxf(sA[2][r], sA[3][r]));
      mx = rmax16(mx);
      float mn = fmaxf(mA[r], mx);
      alA[r] = __expf(mA[r] - mn);
      float ps = 0.f;
      #pragma unroll
      for (int c = 0; c < 4; ++c) {
        float p = __expf(sA[c][r] - mn);
        sA[c][r] = p;
        ps += p;
      }
      ps = rsum16(ps);
      lA[r] = lA[r] * alA[r] + ps;
      mA[r] = mn;
    }
    if (doB) {
      #pragma unroll
      for (int r = 0; r < 4; ++r) {
        float mx = fmaxf(fmaxf(sB[0][r], sB[1][r]), fmaxf(sB[2][r], sB[3][r]));
        mx = rmax16(mx);
        float mn = fmaxf(mB[r], mx);
        alB[r] = __expf(mB[r] - mn);
        float ps = 0.f;
        #pragma unroll
        for (int c = 0; c < 4; ++c) {
          float p = __expf(sB[c][r] - mn);
          sB[c][r] = p;
          ps += p;
        }
        ps = rsum16(ps);
        lB[r] = lB[r] * alB[r] + ps;
        mB[r] = mn;
      }
    }
    // ---- V fragments (shared) ----
    short8 vb0[4], vb1[4];
    #pragma unroll
    for (int c = 0; c < 4; ++c) {
      int n = c * 16 + l15;
      vb0[c] = *reinterpret_cast<const short8*>(&smem[vtb + vrot(n, lg * 8)]);
      vb1[c] = *reinterpret_cast<const short8*>(&smem[vtb + vrot(n, 32 + lg * 8)]);
    }
    // ---- PV A ----
    #pragma unroll
    for (int c = 0; c < 4; ++c) {
      #pragma unroll
      for (int r = 0; r < 4; ++r) {
        smem[PsO + vrot(wv * 16 + lg * 4 + r, c * 16 + l15)] = f2b(sA[c][r]);
        oA[c][r] *= alA[r];
      }
    }
    int prow = wv * 16 + l15;
    {
      short8 ap0 = *reinterpret_cast<const short8*>(&smem[PsO + vrot(prow, lg * 8)]);
      short8 ap1 = *reinterpret_cast<const short8*>(&smem[PsO + vrot(prow, 32 + lg * 8)]);
      #pragma unroll
      for (int c = 0; c < 4; ++c)
        oA[c] = mfma16(ap1, vb1[c], mfma16(ap0, vb0[c], oA[c]));
    }
    // ---- PV B (same Ps rows reused; same-wave ordering) ----
    if (doB) {
      #pragma unroll
      for (int c = 0; c < 4; ++c) {
        #pragma unroll
        for (int r = 0; r < 4; ++r) {
          smem[PsO + vrot(wv * 16 + lg * 4 + r, c * 16 + l15)] = f2b(sB[c][r]);
          oB[c][r] *= alB[r];
        }
      }
      short8 bp0 = *reinterpret_cast<const short8*>(&smem[PsO + vrot(prow, lg * 8)]);
      short8 bp1 = *reinterpret_cast<const short8*>(&smem[PsO + vrot(prow, 32 + lg * 8)]);
      #pragma unroll
      for (int c = 0; c < 4; ++c)
        oB[c] = mfma16(bp1, vb1[c], mfma16(bp0, vb0[c], oB[c]));
    }
    // ---- write prefetched tile into the other buffer ----
    if (kt < qtA) {
      *reinterpret_cast<short8*>(&smem[ksn + kslot0]) = nk0;
      *reinterpret_cast<short8*>(&smem[ksn + kslot1]) = nk1;
      #pragma unroll
      for (int j = 0; j < 8; ++j) smem[vtn + vslot[j]] = (u16)nv0[j];
      #pragma unroll
      for (int j = 0; j < 8; ++j) smem[vtn + vslot[8 + j]] = (u16)nv1[j];
    }
    __syncthreads(); // single barrier per tile
    cur ^= 1;
  }
  #pragma unroll
  for (int r = 0; r < 4; ++r) { lA[r] = 1.0f / lA[r]; lB[r] = 1.0f / lB[r]; }
  #pragma unroll
  for (int c = 0; c < 4; ++c) {
    #pragma unroll
    for (int r = 0; r < 4; ++r) {
      size_t obA = (size_t)(b * SEQ + qsA + lg * 4 + r) * HID + hoff + c * 16 + l15;
      ATT[obA] = f2b(oA[c][r] * lA[r]);
      size_t obB = (size_t)(b * SEQ + qsB + lg * 4 + r) * HID + hoff + c * 16 + l15;
      ATT[obB] = f2b(oB[c][r] * lB[r]);
    }
  }
}

extern "C" void kernel_launch(void* const* d_in, const int* in_sizes, int n_in,
                              void* d_out, int out_size, void* d_ws, size_t ws_size,
                              hipStream_t stream) {
  const float* x      = (const float*)d_in[0];
  const float* Wq     = (const float*)d_in[1];
  const float* bq     = (const float*)d_in[2];
  const float* Wk     = (const float*)d_in[3];
  const float* bk     = (const float*)d_in[4];
  const float* Wv     = (const float*)d_in[5];
  const float* bv     = (const float*)d_in[6];
  const float* Wo     = (const float*)d_in[7];
  const float* bo     = (const float*)d_in[8];
  const float* relpos = (const float*)d_in[9];
  const float* gamma  = (const float*)d_in[10];
  const float* beta   = (const float*)d_in[11];
  const float* Wrk    = (const float*)d_in[12];
  const float* brk    = (const float*)d_in[13];
  const float* Wrq    = (const float*)d_in[14];
  const float* brq    = (const float*)d_in[15];
  float* out = (float*)d_out;

  u16* wsu = (u16*)d_ws;
  size_t off = 0;
  auto alloc = [&](size_t n) { u16* p = wsu + off; off += n; return p; };
  u16* xb   = alloc(4194304);
  u16* Eb   = alloc(524288);
  u16* WtQ  = alloc(1048576);  // contiguous: WtQ|WtK|WtV for merged QKV GEMM
  u16* WtK  = alloc(1048576);
  u16* WtV  = alloc(1048576);
  u16* WtO  = alloc(1048576);
  u16* WtRK = alloc(1048576);  // contiguous: WtRK|WtRQ for merged rel GEMM
  u16* WtRQ = alloc(1048576);
  u16* Qb2  = alloc(4194304);
  u16* Kb2  = alloc(4194304);
  u16* Vb2  = alloc(4194304);
  u16* ATTb = alloc(4194304);
  u16* RKb2 = alloc(524288);
  u16* RQb2 = alloc(524288);
  float* qrk0 = (float*)(wsu + off); off += 131072;
  float* krq0 = (float*)(wsu + off); off += 131072;
  u16* bandT = alloc((size_t)NB * NH * 32 * 9 * 4096); // 75.5 MB tile-layout bias

  ln_kernel<<<512, 256, 0, stream>>>(relpos, gamma, beta, Eb);
  conv_bf16<<<2048, 256, 0, stream>>>(x, xb, 4194304);
  P6 p6;
  p6.s[0] = Wq; p6.s[1] = Wk; p6.s[2] = Wv; p6.s[3] = Wo; p6.s[4] = Wrk; p6.s[5] = Wrq;
  p6.d[0] = WtQ; p6.d[1] = WtK; p6.d[2] = WtV; p6.d[3] = WtO; p6.d[4] = WtRK; p6.d[5] = WtRQ;
  dim3 gT(32, 32, 6);
  transp_all<<<gT, 256, 0, stream>>>(p6);

  GO goQKV = {{bq, bk, bv}, {Qb2, Kb2, Vb2}};
  dim3 gQKV(24, 32); // 768 blocks -> 3 blocks/CU
  gemm_bf16<false><<<gQKV, 512, 0, stream>>>(xb, WtQ, goQKV);
  GO goRel = {{brk, brq, brq}, {RKb2, RQb2, RQb2}};
  dim3 gRel2(16, 4);
  gemm_bf16<false><<<gRel2, 512, 0, stream>>>(Eb, WtRK, goRel);

  biasqk<<<1024, 256, 0, stream>>>(Qb2, Kb2, RKb2, RQb2, qrk0, krq0);

  dim3 gB(32, NH, NB);
  bias_kernel<<<gB, 256, 0, stream>>>(Qb2, Kb2, RKb2, RQb2, bandT);

  dim3 gA(16, NH, NB); // paired q-tiles: 512 balanced blocks
  attn_mfma<<<gA, 256, 0, stream>>>(Qb2, Kb2, Vb2, qrk0, krq0, bandT, ATTb);

  GO goOut = {{bo, bo, bo}, {out, out, out}};
  dim3 gBig(8, 32);
  gemm_bf16<true><<<gBig, 512, 0, stream>>>(ATTb, WtO, goOut);
}